// Round 1
// baseline (567.544 us; speedup 1.0000x reference)
//
#include <hip/hip_runtime.h>
#include <stdint.h>

// ---------------------------------------------------------------------------
// GTU block: rmsnorm -> [u|v] GEMM+silu -> depthwise 2D circular Toeplitz conv
//            -> g = u*conv -> out = g@Wo + bo + x
// Workspace budget ~179 MB.  All heavy GEMMs: bf16 MFMA 16x16x32, 128x128
// tile, BK=64, global_load_lds staging (m97 structure).
// ---------------------------------------------------------------------------

typedef __attribute__((ext_vector_type(4))) float  f32x4;
typedef __attribute__((ext_vector_type(8))) short  s16x8;
typedef __attribute__((ext_vector_type(8))) unsigned short u16x8;
typedef __attribute__((ext_vector_type(4))) unsigned short u16x4;
typedef unsigned short u16;

#define M_TOT 32768      // B*H*W
#define E_DIM 384
#define D1    768
#define NHEAD 6
#define HDIM  128

__device__ __forceinline__ u16 f2bf(float f) {
  union { float f; unsigned int u; } v; v.f = f;
  unsigned int r = (v.u + 0x7FFFu + ((v.u >> 16) & 1u)) >> 16;
  return (u16)r;
}
__device__ __forceinline__ float bf2f(u16 h) {
  union { unsigned int u; float f; } v; v.u = ((unsigned int)h) << 16;
  return v.f;
}
__device__ __forceinline__ float silu_f(float x) { return x / (1.f + expf(-x)); }

__device__ __forceinline__ void gload_lds16(const u16* g, u16* l) {
  __builtin_amdgcn_global_load_lds(
      (const __attribute__((address_space(1))) uint32_t*)g,
      (__attribute__((address_space(3))) uint32_t*)l, 16, 0, 0);
}

// ---------------------------------------------------------------------------
// K1: weight transpose + cast to bf16.
//   Wuvt[n][k] = (n<768 ? Wu : Wv)[k][n'],  n<1536, k<384
//   Wot [n][k] = Wo[k][n],                  n<384,  k<768
// ---------------------------------------------------------------------------
__global__ __launch_bounds__(256) void prep_k(const float* __restrict__ Wu,
                                              const float* __restrict__ Wv,
                                              const float* __restrict__ Wo,
                                              u16* __restrict__ Wuvt,
                                              u16* __restrict__ Wot) {
  int idx = blockIdx.x * 256 + threadIdx.x;
  const int NUV = 1536 * 384;
  if (idx < NUV) {
    int n = idx / 384, k = idx % 384;
    float val = (n < 768) ? Wu[(size_t)k * 768 + n] : Wv[(size_t)k * 768 + (n - 768)];
    Wuvt[idx] = f2bf(val);
  } else {
    int j = idx - NUV;
    if (j < 384 * 768) {
      int n = j / 768, k = j % 768;
      Wot[j] = f2bf(Wo[(size_t)k * 384 + n]);
    }
  }
}

// ---------------------------------------------------------------------------
// K2: SimpleRMSNorm rows of 384, write bf16.  1 wave per row, 4 rows/block.
// ---------------------------------------------------------------------------
__global__ __launch_bounds__(256) void rms_k(const float* __restrict__ x,
                                             u16* __restrict__ xn) {
  int row  = blockIdx.x * 4 + (threadIdx.x >> 6);
  int lane = threadIdx.x & 63;
  const float* xr = x + (size_t)row * 384 + lane;
  float v[6]; float ss = 0.f;
#pragma unroll
  for (int i = 0; i < 6; i++) { v[i] = xr[i * 64]; ss += v[i] * v[i]; }
#pragma unroll
  for (int off = 32; off > 0; off >>= 1) ss += __shfl_xor(ss, off);
  float sc = rsqrtf(ss * (1.f / 384.f) + 1e-6f);
  u16* o = xn + (size_t)row * 384 + lane;
#pragma unroll
  for (int i = 0; i < 6; i++) o[i * 64] = f2bf(v[i] * sc);
}

// ---------------------------------------------------------------------------
// K3: RPE MLP.  256 blocks = {mlp(r1->a_w, r2->a_h)} x {128 position rows}.
// Row p position value: p<64 -> p ; p==64 -> 0 (dummy t_zero) ; else p-128.
// Output layout a[p][768] fp32 (col = h*128+d).
// ---------------------------------------------------------------------------
__global__ __launch_bounds__(512) void rpe_k(
    const float* __restrict__ pw1, const float* __restrict__ pb1,
    const float* __restrict__ lw1, const float* __restrict__ lb1,
    const float* __restrict__ ow1, const float* __restrict__ ob1,
    const float* __restrict__ pw2, const float* __restrict__ pb2,
    const float* __restrict__ lw2, const float* __restrict__ lb2,
    const float* __restrict__ ow2, const float* __restrict__ ob2,
    float* __restrict__ a_w_out, float* __restrict__ a_h_out) {
  int mlp = blockIdx.x >> 7;
  int p   = blockIdx.x & 127;
  const float* pw = mlp ? pw2 : pw1;
  const float* pb = mlp ? pb2 : pb1;
  const float* lw = mlp ? lw2 : lw1;
  const float* lb = mlp ? lb2 : lb1;
  const float* ow = mlp ? ow2 : ow1;
  const float* ob = mlp ? ob2 : ob1;
  float* aout = mlp ? a_h_out : a_w_out;

  int j = threadIdx.x;
  float pos = (p < 64) ? (float)p : ((p == 64) ? 0.f : (float)(p - 128));

  __shared__ float xs[512];
  __shared__ float red[8];

  float xj = fmaxf(pos * pw[j] + pb[j], 0.f);

  for (int L = 0; L < 3; L++) {
    float t = xj * xj;
#pragma unroll
    for (int off = 32; off > 0; off >>= 1) t += __shfl_xor(t, off);
    if ((j & 63) == 0) red[j >> 6] = t;
    __syncthreads();
    float ss = 0.f;
#pragma unroll
    for (int w = 0; w < 8; w++) ss += red[w];
    float sc = rsqrtf(ss * (1.f / 512.f) + 1e-6f);
    xs[j] = fmaxf(xj * sc, 0.f);
    __syncthreads();
    const float* wc = lw + (size_t)L * 512 * 512 + j;
    float acc = lb[L * 512 + j];
#pragma unroll 8
    for (int k = 0; k < 512; k++) acc += xs[k] * wc[k * 512];
    xj = acc;
    __syncthreads();
  }
  // output projection (512 -> 768)
  {
    float t = xj * xj;
#pragma unroll
    for (int off = 32; off > 0; off >>= 1) t += __shfl_xor(t, off);
    if ((j & 63) == 0) red[j >> 6] = t;
    __syncthreads();
    float ss = 0.f;
#pragma unroll
    for (int w = 0; w < 8; w++) ss += red[w];
    float sc = rsqrtf(ss * (1.f / 512.f) + 1e-6f);
    xs[j] = fmaxf(xj * sc, 0.f);
    __syncthreads();
    for (int col = j; col < 768; col += 512) {
      const float* wc = ow + col;
      float acc = ob[col];
#pragma unroll 8
      for (int k = 0; k < 512; k++) acc += xs[k] * wc[k * 768];
      aout[(size_t)p * 768 + col] = acc;
    }
  }
}

// ---------------------------------------------------------------------------
// GEMM: C[m][n] = sum_k A[m][k]*Bt[n][k]  (A bf16 (M,K) k-contig, Bt bf16
// (N,K) k-contig).  128x128 tile, BK=64, 4 waves (2x2), mfma 16x16x32 bf16.
// MODE 0: C -> silu(C+bias); n<768 -> u (M,768); n>=768 -> v_t (768,M) transposed.
// MODE 1: C -> C + bo[n] + x[m][n] -> fp32 out (M,384).
// Epilogue goes through LDS (64 rows x 132 cols fp32) for coalesced stores.
// ---------------------------------------------------------------------------
template <int MODE>
__global__ __launch_bounds__(256) void gemm_k(
    const u16* __restrict__ A, const u16* __restrict__ Bt, int K, int nbn,
    u16* __restrict__ u_out, u16* __restrict__ vt_out,
    const float* __restrict__ bu, const float* __restrict__ bv,
    float* __restrict__ out, const float* __restrict__ bo,
    const float* __restrict__ xres) {
  __shared__ __align__(16) char smem[34816];
  u16*   As  = (u16*)smem;
  u16*   Bs  = As + 128 * 64;
  float* epi = (float*)smem;

  const int tid  = threadIdx.x;
  const int lane = tid & 63;
  const int wid  = tid >> 6;
  const int wm   = wid >> 1, wn = wid & 1;
  const int bm   = blockIdx.x / nbn, bn = blockIdx.x % nbn;  // n-fast for A L2 reuse
  const int m0   = bm * 128, n0 = bn * 128;
  const int fl   = lane & 15, fh = lane >> 4;

  f32x4 acc[4][4];
  {
    f32x4 z = {0.f, 0.f, 0.f, 0.f};
#pragma unroll
    for (int i = 0; i < 4; i++)
#pragma unroll
      for (int j = 0; j < 4; j++) acc[i][j] = z;
  }

  const int sr = tid >> 3;          // staging row 0..31
  const int sc = (tid & 7) * 8;     // staging col (bf16 elems), 16B chunks

  for (int kt = 0; kt < K; kt += 64) {
    const u16* gA = A  + (size_t)(m0 + sr) * K + kt + sc;
    const u16* gB = Bt + (size_t)(n0 + sr) * K + kt + sc;
    u16* lA = As + sr * 64 + sc;
    u16* lB = Bs + sr * 64 + sc;
#pragma unroll
    for (int i = 0; i < 4; i++) {
      gload_lds16(gA + (size_t)(i * 32) * K, lA + i * 32 * 64);
      gload_lds16(gB + (size_t)(i * 32) * K, lB + i * 32 * 64);
    }
    __syncthreads();
#pragma unroll
    for (int ks = 0; ks < 2; ks++) {
      s16x8 af[4], bfr[4];
      const u16* ap = As + (wm * 64 + fl) * 64 + ks * 32 + fh * 8;
      const u16* bp = Bs + (wn * 64 + fl) * 64 + ks * 32 + fh * 8;
#pragma unroll
      for (int i = 0; i < 4; i++) af[i] = *(const s16x8*)(ap + i * 16 * 64);
#pragma unroll
      for (int j = 0; j < 4; j++) bfr[j] = *(const s16x8*)(bp + j * 16 * 64);
#pragma unroll
      for (int i = 0; i < 4; i++)
#pragma unroll
        for (int j = 0; j < 4; j++)
          acc[i][j] = __builtin_amdgcn_mfma_f32_16x16x32_bf16(af[i], bfr[j], acc[i][j], 0, 0, 0);
    }
    __syncthreads();
  }

  // ---- epilogue: two halves (wm groups) through LDS 64x132 fp32 ----
  for (int half = 0; half < 2; half++) {
    __syncthreads();
    if (wm == half) {
#pragma unroll
      for (int i = 0; i < 4; i++)
#pragma unroll
        for (int j = 0; j < 4; j++) {
          int er = i * 16 + fh * 4;
          int ec = wn * 64 + j * 16 + fl;
#pragma unroll
          for (int q = 0; q < 4; q++) epi[(er + q) * 132 + ec] = acc[i][j][q];
        }
    }
    __syncthreads();
    if (MODE == 0) {
      if (n0 < 768) {  // -> u (M,768)
        int rr = tid >> 2;
        int gm = m0 + half * 64 + rr;
        u16* dst = u_out + (size_t)gm * 768 + n0;
#pragma unroll
        for (int q = 0; q < 4; q++) {
          int cb = (tid & 3) * 8 + q * 32;
          u16x8 pk;
#pragma unroll
          for (int e = 0; e < 8; e++) {
            int c = cb + e;
            pk[e] = f2bf(silu_f(epi[rr * 132 + c] + bu[n0 + c]));
          }
          *(u16x8*)(dst + cb) = pk;
        }
      } else {         // -> v_t (768, M) transposed
        int cc = tid >> 1;
        int cg = n0 - 768 + cc;
        float bias = bv[cg];
        u16* dst = vt_out + (size_t)cg * M_TOT + m0 + half * 64;
#pragma unroll
        for (int q = 0; q < 4; q++) {
          int mb = (tid & 1) * 8 + q * 16;
          u16x8 pk;
#pragma unroll
          for (int e = 0; e < 8; e++) {
            int mm = mb + e;
            pk[e] = f2bf(silu_f(epi[mm * 132 + cc] + bias));
          }
          *(u16x8*)(dst + mb) = pk;
        }
      }
    } else {  // MODE 1: + bo + x -> fp32
      int rr = tid >> 2;
      int gm = m0 + half * 64 + rr;
      const float* xr = xres + (size_t)gm * 384 + n0;
      float* orow = out + (size_t)gm * 384 + n0;
#pragma unroll
      for (int q = 0; q < 8; q++) {
        int cb = (tid & 3) * 4 + q * 16;
        f32x4 xv = *(const f32x4*)(xr + cb);
        f32x4 ov;
#pragma unroll
        for (int e = 0; e < 4; e++) {
          int c = cb + e;
          ov[e] = epi[rr * 132 + c] + bo[n0 + c] + xv[e];
        }
        *(f32x4*)(orow + cb) = ov;
      }
    }
  }
}

// ---------------------------------------------------------------------------
// K5: depthwise circular Toeplitz conv (H and W, 64 taps each, mod-128 table).
// Block = (b, h, dt): 2 channels, full 64x64 spatial slab in LDS (padded 68).
// Reads v_t (C,M) bf16, writes cs_t (C,M) bf16.  out[y][x] =
//   sum_j ah[(y-j)&127]*slab[j][x] + sum_j aw[(x-j)&127]*slab[y][j]
// ---------------------------------------------------------------------------
__global__ __launch_bounds__(256) void conv_k(const u16* __restrict__ vt,
                                              const float* __restrict__ a_h,
                                              const float* __restrict__ a_w,
                                              u16* __restrict__ cst) {
  __shared__ float slab[2][64 * 68];
  __shared__ float ahs[2][128];
  __shared__ float aws[2][128];
  const int tid = threadIdx.x;
  int bid = blockIdx.x;
  int b   = bid / 384;
  int rem = bid % 384;
  int h   = rem / 64;
  int dt  = rem % 64;
  int cg  = h * 128 + dt * 2;

#pragma unroll
  for (int c = 0; c < 2; c++) {
    const u16* src = vt + (size_t)(cg + c) * M_TOT + b * 4096;
    for (int p = tid; p < 4096; p += 256)
      slab[c][(p >> 6) * 68 + (p & 63)] = bf2f(src[p]);
  }
  {
    int c = tid >> 7, p = tid & 127;
    ahs[c][p] = a_h[(size_t)p * 768 + cg + c];
    aws[c][p] = a_w[(size_t)p * 768 + cg + c];
  }
  __syncthreads();

  int tx = tid & 15, ty = tid >> 4;
  int x0 = tx * 4, y0 = ty * 4;
  float acc[2][4][4];
#pragma unroll
  for (int c = 0; c < 2; c++)
#pragma unroll
    for (int dy = 0; dy < 4; dy++)
#pragma unroll
      for (int dx = 0; dx < 4; dx++) acc[c][dy][dx] = 0.f;

#pragma unroll
  for (int c = 0; c < 2; c++) {
    const float* sl = slab[c];
    const float* ah = ahs[c];
    const float* aw = aws[c];
#pragma unroll 4
    for (int j = 0; j < 64; j++) {      // H-conv
      f32x4 s = *(const f32x4*)(sl + j * 68 + x0);
#pragma unroll
      for (int dy = 0; dy < 4; dy++) {
        float a = ah[(y0 + dy - j) & 127];
        acc[c][dy][0] += a * s[0];
        acc[c][dy][1] += a * s[1];
        acc[c][dy][2] += a * s[2];
        acc[c][dy][3] += a * s[3];
      }
    }
#pragma unroll 4
    for (int j = 0; j < 64; j++) {      // W-conv
      float a0 = aw[(x0 + 0 - j) & 127];
      float a1 = aw[(x0 + 1 - j) & 127];
      float a2 = aw[(x0 + 2 - j) & 127];
      float a3 = aw[(x0 + 3 - j) & 127];
#pragma unroll
      for (int dy = 0; dy < 4; dy++) {
        float sv = sl[(y0 + dy) * 68 + j];
        acc[c][dy][0] += a0 * sv;
        acc[c][dy][1] += a1 * sv;
        acc[c][dy][2] += a2 * sv;
        acc[c][dy][3] += a3 * sv;
      }
    }
  }

#pragma unroll
  for (int c = 0; c < 2; c++) {
#pragma unroll
    for (int dy = 0; dy < 4; dy++) {
      u16x4 pk;
      pk[0] = f2bf(acc[c][dy][0]);
      pk[1] = f2bf(acc[c][dy][1]);
      pk[2] = f2bf(acc[c][dy][2]);
      pk[3] = f2bf(acc[c][dy][3]);
      *(u16x4*)(cst + (size_t)(cg + c) * M_TOT + b * 4096 + (y0 + dy) * 64 + x0) = pk;
    }
  }
}

// ---------------------------------------------------------------------------
// K6: g[m][c] = bf16( u[m][c] * cs_t[c][m] )   (64x64 tiles, LDS transpose)
// ---------------------------------------------------------------------------
__global__ __launch_bounds__(256) void transmul_k(const u16* __restrict__ cst,
                                                  const u16* __restrict__ u,
                                                  u16* __restrict__ g) {
  __shared__ u16 ct[64 * 72];
  const int tid = threadIdx.x;
  int bm = blockIdx.x / 12, bc = blockIdx.x % 12;
  int m0 = bm * 64, c0 = bc * 64;
  {
    int cc = tid >> 2, sg = (tid & 3) * 8;
    const u16* src = cst + (size_t)(c0 + cc) * M_TOT + m0 + sg;
    *(u16x8*)(ct + cc * 72 + sg)      = *(const u16x8*)(src);
    *(u16x8*)(ct + cc * 72 + sg + 32) = *(const u16x8*)(src + 32);
  }
  __syncthreads();
  int mr = tid >> 2;
  int gm = m0 + mr;
  const u16* up = u + (size_t)gm * 768 + c0;
  u16* gp = g + (size_t)gm * 768 + c0;
#pragma unroll
  for (int q = 0; q < 2; q++) {
    int cb = (tid & 3) * 8 + q * 32;
    u16x8 uv = *(const u16x8*)(up + cb);
    u16x8 pk;
#pragma unroll
    for (int e = 0; e < 8; e++) {
      int c = cb + e;
      pk[e] = f2bf(bf2f(uv[e]) * bf2f(ct[c * 72 + mr]));
    }
    *(u16x8*)(gp + cb) = pk;
  }
}

// ---------------------------------------------------------------------------
extern "C" void kernel_launch(void* const* d_in, const int* in_sizes, int n_in,
                              void* d_out, int out_size, void* d_ws, size_t ws_size,
                              hipStream_t stream) {
  const float* x    = (const float*)d_in[0];
  // d_in[1]=H, d_in[2]=W (compile-time constants here)
  const float* Wu   = (const float*)d_in[3];
  const float* bu   = (const float*)d_in[4];
  const float* Wv   = (const float*)d_in[5];
  const float* bv   = (const float*)d_in[6];
  const float* Wo   = (const float*)d_in[7];
  const float* bo   = (const float*)d_in[8];
  const float* r1pw = (const float*)d_in[9];
  const float* r1pb = (const float*)d_in[10];
  const float* r1lw = (const float*)d_in[11];
  const float* r1lb = (const float*)d_in[12];
  const float* r1ow = (const float*)d_in[13];
  const float* r1ob = (const float*)d_in[14];
  const float* r2pw = (const float*)d_in[15];
  const float* r2pb = (const float*)d_in[16];
  const float* r2lw = (const float*)d_in[17];
  const float* r2lb = (const float*)d_in[18];
  const float* r2ow = (const float*)d_in[19];
  const float* r2ob = (const float*)d_in[20];
  float* outp = (float*)d_out;

  // workspace carve-up (~179 MB)
  char* ws = (char*)d_ws;
  size_t off = 0;
  auto carve = [&](size_t bytes) {
    char* p = ws + off;
    off += (bytes + 255) & ~(size_t)255;
    return p;
  };
  u16*   xn   = (u16*)carve((size_t)M_TOT * 384 * 2);
  u16*   u    = (u16*)carve((size_t)M_TOT * 768 * 2);
  u16*   vt   = (u16*)carve((size_t)768 * M_TOT * 2);
  u16*   cst  = (u16*)carve((size_t)768 * M_TOT * 2);
  u16*   Wuvt = (u16*)carve((size_t)1536 * 384 * 2);
  u16*   Wot  = (u16*)carve((size_t)384 * 768 * 2);
  float* aw_t = (float*)carve((size_t)128 * 768 * 4);
  float* ah_t = (float*)carve((size_t)128 * 768 * 4);
  u16*   g    = vt;  // alias: v_t dead after conv_k

  prep_k<<<3456, 256, 0, stream>>>(Wu, Wv, Wo, Wuvt, Wot);
  rms_k<<<8192, 256, 0, stream>>>(x, xn);
  rpe_k<<<256, 512, 0, stream>>>(r1pw, r1pb, r1lw, r1lb, r1ow, r1ob,
                                 r2pw, r2pb, r2lw, r2lb, r2ow, r2ob,
                                 aw_t, ah_t);
  // u|v GEMM: M=32768, N=1536, K=384
  gemm_k<0><<<256 * 12, 256, 0, stream>>>(xn, Wuvt, 384, 12,
                                          u, vt, bu, bv,
                                          nullptr, nullptr, nullptr);
  conv_k<<<8 * 6 * 64, 256, 0, stream>>>(vt, ah_t, aw_t, cst);
  transmul_k<<<512 * 12, 256, 0, stream>>>(cst, u, g);
  // out GEMM: M=32768, N=384, K=768 (+bo +x residual)
  gemm_k<1><<<256 * 3, 256, 0, stream>>>(g, Wot, 768, 3,
                                         nullptr, nullptr, nullptr, nullptr,
                                         outp, bo, x);
}

// Round 2
// 526.569 us; speedup vs baseline: 1.0778x; 1.0778x over previous
//
#include <hip/hip_runtime.h>
#include <stdint.h>

// ---------------------------------------------------------------------------
// GTU block: rmsnorm -> [u|v] GEMM+silu -> depthwise 2D circular Toeplitz conv
//            -> g = u*conv -> out = g@Wo + bo + x
// R2: RPE MLP rewritten as batched bf16 MFMA GEMM (was 172us GEMV farm with
//     zero weight reuse -> ~1GB L3 traffic; now ~2MB, 5 tiny launches).
// ---------------------------------------------------------------------------

typedef __attribute__((ext_vector_type(4))) float  f32x4;
typedef __attribute__((ext_vector_type(8))) short  s16x8;
typedef __attribute__((ext_vector_type(8))) unsigned short u16x8;
typedef __attribute__((ext_vector_type(4))) unsigned short u16x4;
typedef unsigned short u16;

#define M_TOT 32768      // B*H*W
#define E_DIM 384
#define D1    768
#define NHEAD 6
#define HDIM  128

__device__ __forceinline__ u16 f2bf(float f) {
  union { float f; unsigned int u; } v; v.f = f;
  unsigned int r = (v.u + 0x7FFFu + ((v.u >> 16) & 1u)) >> 16;
  return (u16)r;
}
__device__ __forceinline__ float bf2f(u16 h) {
  union { unsigned int u; float f; } v; v.u = ((unsigned int)h) << 16;
  return v.f;
}
__device__ __forceinline__ float silu_f(float x) { return x / (1.f + expf(-x)); }

__device__ __forceinline__ void gload_lds16(const u16* g, u16* l) {
  __builtin_amdgcn_global_load_lds(
      (const __attribute__((address_space(1))) uint32_t*)g,
      (__attribute__((address_space(3))) uint32_t*)l, 16, 0, 0);
}

// ---------------------------------------------------------------------------
// K1: main weight transpose + cast to bf16.
// ---------------------------------------------------------------------------
__global__ __launch_bounds__(256) void prep_k(const float* __restrict__ Wu,
                                              const float* __restrict__ Wv,
                                              const float* __restrict__ Wo,
                                              u16* __restrict__ Wuvt,
                                              u16* __restrict__ Wot) {
  int idx = blockIdx.x * 256 + threadIdx.x;
  const int NUV = 1536 * 384;
  if (idx < NUV) {
    int n = idx / 384, k = idx % 384;
    float val = (n < 768) ? Wu[(size_t)k * 768 + n] : Wv[(size_t)k * 768 + (n - 768)];
    Wuvt[idx] = f2bf(val);
  } else {
    int j = idx - NUV;
    if (j < 384 * 768) {
      int n = j / 768, k = j % 768;
      Wot[j] = f2bf(Wo[(size_t)k * 384 + n]);
    }
  }
}

// ---------------------------------------------------------------------------
// K1b: RPE weight transpose (tiled, coalesced both sides) fp32 -> bf16.
//  lwT[mlp][L][n][k] = lw_mlp[L][k][n]   (512x512 each)
//  owT[mlp][n][k]    = ow_mlp[k][n]      (512x768 -> 768x512)
// grid 2304 = 2 mlp x (3*256 lw-tiles + 384 ow-tiles), 32x32 tiles.
// ---------------------------------------------------------------------------
__global__ __launch_bounds__(256) void rpet_k(const float* __restrict__ r1lw,
                                              const float* __restrict__ r1ow,
                                              const float* __restrict__ r2lw,
                                              const float* __restrict__ r2ow,
                                              u16* __restrict__ lwT,
                                              u16* __restrict__ owT) {
  __shared__ float sm[32][33];
  int b = blockIdx.x;
  int mlp = b / 1152;
  int r = b % 1152;
  const float* src;
  u16* dst;
  int C, ty, tx;
  if (r < 768) {
    int L = r / 256, t = r % 256;
    ty = t / 16; tx = t % 16;
    src = (mlp ? r2lw : r1lw) + (size_t)L * 262144;
    dst = lwT + (size_t)(mlp * 3 + L) * 262144;
    C = 512;
  } else {
    int t = r - 768;
    ty = t / 24; tx = t % 24;
    src = mlp ? r2ow : r1ow;
    dst = owT + (size_t)mlp * 393216;
    C = 768;
  }
  int lx = threadIdx.x % 32, ly = threadIdx.x / 32;
#pragma unroll
  for (int q = 0; q < 4; q++) {
    int y = q * 8 + ly;
    sm[y][lx] = src[(size_t)(ty * 32 + y) * C + tx * 32 + lx];
  }
  __syncthreads();
#pragma unroll
  for (int q = 0; q < 4; q++) {
    int y = q * 8 + ly;
    dst[(size_t)(tx * 32 + y) * 512 + ty * 32 + lx] = f2bf(sm[lx][y]);
  }
}

// ---------------------------------------------------------------------------
// K2: SimpleRMSNorm rows of 384, write bf16.  1 wave per row, 4 rows/block.
// ---------------------------------------------------------------------------
__global__ __launch_bounds__(256) void rms_k(const float* __restrict__ x,
                                             u16* __restrict__ xn) {
  int row  = blockIdx.x * 4 + (threadIdx.x >> 6);
  int lane = threadIdx.x & 63;
  const float* xr = x + (size_t)row * 384 + lane;
  float v[6]; float ss = 0.f;
#pragma unroll
  for (int i = 0; i < 6; i++) { v[i] = xr[i * 64]; ss += v[i] * v[i]; }
#pragma unroll
  for (int off = 32; off > 0; off >>= 1) ss += __shfl_xor(ss, off);
  float sc = rsqrtf(ss * (1.f / 384.f) + 1e-6f);
  u16* o = xn + (size_t)row * 384 + lane;
#pragma unroll
  for (int i = 0; i < 6; i++) o[i * 64] = f2bf(v[i] * sc);
}

// ---------------------------------------------------------------------------
// K3a: RPE input layer: X0[mlp*128+p][j] = relu(pos_p * pw_mlp[j] + pb_mlp[j])
// ---------------------------------------------------------------------------
__global__ __launch_bounds__(256) void rpe_in_k(const float* __restrict__ r1pw,
                                                const float* __restrict__ r1pb,
                                                const float* __restrict__ r2pw,
                                                const float* __restrict__ r2pb,
                                                float* __restrict__ X0) {
  int idx = blockIdx.x * 256 + threadIdx.x;   // 32768 threads x 4 floats
  int gid = idx * 4;
  int row = gid >> 9, col = gid & 511;
  int mlp = row >> 7, p = row & 127;
  float pos = (p < 64) ? (float)p : ((p == 64) ? 0.f : (float)(p - 128));
  const float* pw = (mlp ? r2pw : r1pw) + col;
  const float* pb = (mlp ? r2pb : r1pb) + col;
  f32x4 w = *(const f32x4*)pw;
  f32x4 bb = *(const f32x4*)pb;
  f32x4 o;
#pragma unroll
  for (int e = 0; e < 4; e++) o[e] = fmaxf(pos * w[e] + bb[e], 0.f);
  *(f32x4*)(X0 + gid) = o;
}

// ---------------------------------------------------------------------------
// K3b: RPE layer GEMM.  X (256x512 fp32, rows = mlp*128+p)
//   out = relu(srms(X_mlp)) @ WT_mlp^T + bias_mlp
// WT is (N x 512) bf16 k-contig.  Tile 128(M) x 128(N), BK=64, 4 waves.
// grid = 2 * (N/128).   outA = mlp0 dest, outB = mlp1 dest (row-major N cols).
// ---------------------------------------------------------------------------
template <int N>
__global__ __launch_bounds__(256) void rpe_layer_k(
    const float* __restrict__ X,
    const u16* __restrict__ wtA, const u16* __restrict__ wtB,
    const float* __restrict__ bA, const float* __restrict__ bB,
    float* __restrict__ outA, float* __restrict__ outB) {
  constexpr int NT = N / 128;
  const int mlp = blockIdx.x / NT;
  const int n0  = (blockIdx.x % NT) * 128;
  const u16* WT = mlp ? wtB : wtA;
  const float* bias = mlp ? bB : bA;
  float* out = mlp ? outB : outA;
  const float* Xm = X + (size_t)mlp * 128 * 512;

  __shared__ float scale[128];
  __shared__ __align__(16) u16 As[128 * 64];
  __shared__ __align__(16) u16 Bs[128 * 64];

  const int tid  = threadIdx.x;
  const int lane = tid & 63;
  const int wid  = tid >> 6;
  const int wm   = wid >> 1, wn = wid & 1;
  const int fl   = lane & 15, fh = lane >> 4;

  // ---- per-row sumsq -> scale ----
  {
    int row = tid >> 1, half = tid & 1;
    const float* xr = Xm + (size_t)row * 512 + half * 256;
    float ss = 0.f;
#pragma unroll 8
    for (int q = 0; q < 64; q++) {
      f32x4 v = *(const f32x4*)(xr + q * 4);
      ss += v[0] * v[0] + v[1] * v[1] + v[2] * v[2] + v[3] * v[3];
    }
    ss += __shfl_xor(ss, 1);
    if (!half) scale[row] = rsqrtf(ss * (1.f / 512.f) + 1e-6f);
  }
  __syncthreads();

  f32x4 acc[4][4];
  {
    f32x4 z = {0.f, 0.f, 0.f, 0.f};
#pragma unroll
    for (int i = 0; i < 4; i++)
#pragma unroll
      for (int j = 0; j < 4; j++) acc[i][j] = z;
  }

  const int arow = tid >> 1, acb = (tid & 1) * 32;   // A staging
  const int sr = tid >> 3, sc = (tid & 7) * 8;       // B staging

  for (int kt = 0; kt < 512; kt += 64) {
    // A: relu(x)*scale -> bf16 -> LDS
    {
      const float* xp = Xm + (size_t)arow * 512 + kt + acb;
      float s_ = scale[arow];
      u16* dst = As + arow * 64 + acb;
#pragma unroll
      for (int q = 0; q < 8; q++) {
        f32x4 v = *(const f32x4*)(xp + q * 4);
        u16x4 pk;
#pragma unroll
        for (int e = 0; e < 4; e++) pk[e] = f2bf(fmaxf(v[e], 0.f) * s_);
        *(u16x4*)(dst + q * 4) = pk;
      }
    }
    // B: global_load_lds
    {
      const u16* gB = WT + (size_t)(n0 + sr) * 512 + kt + sc;
      u16* lB = Bs + sr * 64 + sc;
#pragma unroll
      for (int i = 0; i < 4; i++)
        gload_lds16(gB + (size_t)(i * 32) * 512, lB + i * 32 * 64);
    }
    __syncthreads();
#pragma unroll
    for (int ks = 0; ks < 2; ks++) {
      s16x8 af[4], bfr[4];
      const u16* ap = As + (wm * 64 + fl) * 64 + ks * 32 + fh * 8;
      const u16* bp = Bs + (wn * 64 + fl) * 64 + ks * 32 + fh * 8;
#pragma unroll
      for (int i = 0; i < 4; i++) af[i] = *(const s16x8*)(ap + i * 16 * 64);
#pragma unroll
      for (int j = 0; j < 4; j++) bfr[j] = *(const s16x8*)(bp + j * 16 * 64);
#pragma unroll
      for (int i = 0; i < 4; i++)
#pragma unroll
        for (int j = 0; j < 4; j++)
          acc[i][j] = __builtin_amdgcn_mfma_f32_16x16x32_bf16(af[i], bfr[j], acc[i][j], 0, 0, 0);
    }
    __syncthreads();
  }

  // ---- epilogue: +bias, direct fp32 stores ----
#pragma unroll
  for (int i = 0; i < 4; i++)
#pragma unroll
    for (int j = 0; j < 4; j++) {
      int c = n0 + wn * 64 + j * 16 + fl;
      float bv_ = bias[c];
#pragma unroll
      for (int q = 0; q < 4; q++) {
        int r = wm * 64 + i * 16 + fh * 4 + q;
        out[(size_t)r * N + c] = acc[i][j][q] + bv_;
      }
    }
}

// ---------------------------------------------------------------------------
// GEMM: C[m][n] = sum_k A[m][k]*Bt[n][k]  (A bf16 (M,K) k-contig, Bt bf16
// (N,K) k-contig).  128x128 tile, BK=64, 4 waves (2x2), mfma 16x16x32 bf16.
// MODE 0: C -> silu(C+bias); n<768 -> u (M,768); n>=768 -> v_t (768,M) transposed.
// MODE 1: C -> C + bo[n] + x[m][n] -> fp32 out (M,384).
// ---------------------------------------------------------------------------
template <int MODE>
__global__ __launch_bounds__(256) void gemm_k(
    const u16* __restrict__ A, const u16* __restrict__ Bt, int K, int nbn,
    u16* __restrict__ u_out, u16* __restrict__ vt_out,
    const float* __restrict__ bu, const float* __restrict__ bv,
    float* __restrict__ out, const float* __restrict__ bo,
    const float* __restrict__ xres) {
  __shared__ __align__(16) char smem[34816];
  u16*   As  = (u16*)smem;
  u16*   Bs  = As + 128 * 64;
  float* epi = (float*)smem;

  const int tid  = threadIdx.x;
  const int lane = tid & 63;
  const int wid  = tid >> 6;
  const int wm   = wid >> 1, wn = wid & 1;
  const int bm   = blockIdx.x / nbn, bn = blockIdx.x % nbn;
  const int m0   = bm * 128, n0 = bn * 128;
  const int fl   = lane & 15, fh = lane >> 4;

  f32x4 acc[4][4];
  {
    f32x4 z = {0.f, 0.f, 0.f, 0.f};
#pragma unroll
    for (int i = 0; i < 4; i++)
#pragma unroll
      for (int j = 0; j < 4; j++) acc[i][j] = z;
  }

  const int sr = tid >> 3;
  const int sc = (tid & 7) * 8;

  for (int kt = 0; kt < K; kt += 64) {
    const u16* gA = A  + (size_t)(m0 + sr) * K + kt + sc;
    const u16* gB = Bt + (size_t)(n0 + sr) * K + kt + sc;
    u16* lA = As + sr * 64 + sc;
    u16* lB = Bs + sr * 64 + sc;
#pragma unroll
    for (int i = 0; i < 4; i++) {
      gload_lds16(gA + (size_t)(i * 32) * K, lA + i * 32 * 64);
      gload_lds16(gB + (size_t)(i * 32) * K, lB + i * 32 * 64);
    }
    __syncthreads();
#pragma unroll
    for (int ks = 0; ks < 2; ks++) {
      s16x8 af[4], bfr[4];
      const u16* ap = As + (wm * 64 + fl) * 64 + ks * 32 + fh * 8;
      const u16* bp = Bs + (wn * 64 + fl) * 64 + ks * 32 + fh * 8;
#pragma unroll
      for (int i = 0; i < 4; i++) af[i] = *(const s16x8*)(ap + i * 16 * 64);
#pragma unroll
      for (int j = 0; j < 4; j++) bfr[j] = *(const s16x8*)(bp + j * 16 * 64);
#pragma unroll
      for (int i = 0; i < 4; i++)
#pragma unroll
        for (int j = 0; j < 4; j++)
          acc[i][j] = __builtin_amdgcn_mfma_f32_16x16x32_bf16(af[i], bfr[j], acc[i][j], 0, 0, 0);
    }
    __syncthreads();
  }

  for (int half = 0; half < 2; half++) {
    __syncthreads();
    if (wm == half) {
#pragma unroll
      for (int i = 0; i < 4; i++)
#pragma unroll
        for (int j = 0; j < 4; j++) {
          int er = i * 16 + fh * 4;
          int ec = wn * 64 + j * 16 + fl;
#pragma unroll
          for (int q = 0; q < 4; q++) epi[(er + q) * 132 + ec] = acc[i][j][q];
        }
    }
    __syncthreads();
    if (MODE == 0) {
      if (n0 < 768) {
        int rr = tid >> 2;
        int gm = m0 + half * 64 + rr;
        u16* dst = u_out + (size_t)gm * 768 + n0;
#pragma unroll
        for (int q = 0; q < 4; q++) {
          int cb = (tid & 3) * 8 + q * 32;
          u16x8 pk;
#pragma unroll
          for (int e = 0; e < 8; e++) {
            int c = cb + e;
            pk[e] = f2bf(silu_f(epi[rr * 132 + c] + bu[n0 + c]));
          }
          *(u16x8*)(dst + cb) = pk;
        }
      } else {
        int cc = tid >> 1;
        int cg = n0 - 768 + cc;
        float bias = bv[cg];
        u16* dst = vt_out + (size_t)cg * M_TOT + m0 + half * 64;
#pragma unroll
        for (int q = 0; q < 4; q++) {
          int mb = (tid & 1) * 8 + q * 16;
          u16x8 pk;
#pragma unroll
          for (int e = 0; e < 8; e++) {
            int mm = mb + e;
            pk[e] = f2bf(silu_f(epi[mm * 132 + cc] + bias));
          }
          *(u16x8*)(dst + mb) = pk;
        }
      }
    } else {
      int rr = tid >> 2;
      int gm = m0 + half * 64 + rr;
      const float* xr = xres + (size_t)gm * 384 + n0;
      float* orow = out + (size_t)gm * 384 + n0;
#pragma unroll
      for (int q = 0; q < 8; q++) {
        int cb = (tid & 3) * 4 + q * 16;
        f32x4 xv = *(const f32x4*)(xr + cb);
        f32x4 ov;
#pragma unroll
        for (int e = 0; e < 4; e++) {
          int c = cb + e;
          ov[e] = epi[rr * 132 + c] + bo[n0 + c] + xv[e];
        }
        *(f32x4*)(orow + cb) = ov;
      }
    }
  }
}

// ---------------------------------------------------------------------------
// K5: depthwise circular Toeplitz conv (H and W, 64 taps each, mod-128 table).
// ---------------------------------------------------------------------------
__global__ __launch_bounds__(256) void conv_k(const u16* __restrict__ vt,
                                              const float* __restrict__ a_h,
                                              const float* __restrict__ a_w,
                                              u16* __restrict__ cst) {
  __shared__ float slab[2][64 * 68];
  __shared__ float ahs[2][128];
  __shared__ float aws[2][128];
  const int tid = threadIdx.x;
  int bid = blockIdx.x;
  int b   = bid / 384;
  int rem = bid % 384;
  int h   = rem / 64;
  int dt  = rem % 64;
  int cg  = h * 128 + dt * 2;

#pragma unroll
  for (int c = 0; c < 2; c++) {
    const u16* src = vt + (size_t)(cg + c) * M_TOT + b * 4096;
    for (int p = tid; p < 4096; p += 256)
      slab[c][(p >> 6) * 68 + (p & 63)] = bf2f(src[p]);
  }
  {
    int c = tid >> 7, p = tid & 127;
    ahs[c][p] = a_h[(size_t)p * 768 + cg + c];
    aws[c][p] = a_w[(size_t)p * 768 + cg + c];
  }
  __syncthreads();

  int tx = tid & 15, ty = tid >> 4;
  int x0 = tx * 4, y0 = ty * 4;
  float acc[2][4][4];
#pragma unroll
  for (int c = 0; c < 2; c++)
#pragma unroll
    for (int dy = 0; dy < 4; dy++)
#pragma unroll
      for (int dx = 0; dx < 4; dx++) acc[c][dy][dx] = 0.f;

#pragma unroll
  for (int c = 0; c < 2; c++) {
    const float* sl = slab[c];
    const float* ah = ahs[c];
    const float* aw = aws[c];
#pragma unroll 4
    for (int j = 0; j < 64; j++) {
      f32x4 s = *(const f32x4*)(sl + j * 68 + x0);
#pragma unroll
      for (int dy = 0; dy < 4; dy++) {
        float a = ah[(y0 + dy - j) & 127];
        acc[c][dy][0] += a * s[0];
        acc[c][dy][1] += a * s[1];
        acc[c][dy][2] += a * s[2];
        acc[c][dy][3] += a * s[3];
      }
    }
#pragma unroll 4
    for (int j = 0; j < 64; j++) {
      float a0 = aw[(x0 + 0 - j) & 127];
      float a1 = aw[(x0 + 1 - j) & 127];
      float a2 = aw[(x0 + 2 - j) & 127];
      float a3 = aw[(x0 + 3 - j) & 127];
#pragma unroll
      for (int dy = 0; dy < 4; dy++) {
        float sv = sl[(y0 + dy) * 68 + j];
        acc[c][dy][0] += a0 * sv;
        acc[c][dy][1] += a1 * sv;
        acc[c][dy][2] += a2 * sv;
        acc[c][dy][3] += a3 * sv;
      }
    }
  }

#pragma unroll
  for (int c = 0; c < 2; c++) {
#pragma unroll
    for (int dy = 0; dy < 4; dy++) {
      u16x4 pk;
      pk[0] = f2bf(acc[c][dy][0]);
      pk[1] = f2bf(acc[c][dy][1]);
      pk[2] = f2bf(acc[c][dy][2]);
      pk[3] = f2bf(acc[c][dy][3]);
      *(u16x4*)(cst + (size_t)(cg + c) * M_TOT + b * 4096 + (y0 + dy) * 64 + x0) = pk;
    }
  }
}

// ---------------------------------------------------------------------------
// K6: g[m][c] = bf16( u[m][c] * cs_t[c][m] )
// ---------------------------------------------------------------------------
__global__ __launch_bounds__(256) void transmul_k(const u16* __restrict__ cst,
                                                  const u16* __restrict__ u,
                                                  u16* __restrict__ g) {
  __shared__ u16 ct[64 * 72];
  const int tid = threadIdx.x;
  int bm = blockIdx.x / 12, bc = blockIdx.x % 12;
  int m0 = bm * 64, c0 = bc * 64;
  {
    int cc = tid >> 2, sg = (tid & 3) * 8;
    const u16* src = cst + (size_t)(c0 + cc) * M_TOT + m0 + sg;
    *(u16x8*)(ct + cc * 72 + sg)      = *(const u16x8*)(src);
    *(u16x8*)(ct + cc * 72 + sg + 32) = *(const u16x8*)(src + 32);
  }
  __syncthreads();
  int mr = tid >> 2;
  int gm = m0 + mr;
  const u16* up = u + (size_t)gm * 768 + c0;
  u16* gp = g + (size_t)gm * 768 + c0;
#pragma unroll
  for (int q = 0; q < 2; q++) {
    int cb = (tid & 3) * 8 + q * 32;
    u16x8 uv = *(const u16x8*)(up + cb);
    u16x8 pk;
#pragma unroll
    for (int e = 0; e < 8; e++) {
      int c = cb + e;
      pk[e] = f2bf(bf2f(uv[e]) * bf2f(ct[c * 72 + mr]));
    }
    *(u16x8*)(gp + cb) = pk;
  }
}

// ---------------------------------------------------------------------------
extern "C" void kernel_launch(void* const* d_in, const int* in_sizes, int n_in,
                              void* d_out, int out_size, void* d_ws, size_t ws_size,
                              hipStream_t stream) {
  const float* x    = (const float*)d_in[0];
  const float* Wu   = (const float*)d_in[3];
  const float* bu   = (const float*)d_in[4];
  const float* Wv   = (const float*)d_in[5];
  const float* bv   = (const float*)d_in[6];
  const float* Wo   = (const float*)d_in[7];
  const float* bo   = (const float*)d_in[8];
  const float* r1pw = (const float*)d_in[9];
  const float* r1pb = (const float*)d_in[10];
  const float* r1lw = (const float*)d_in[11];
  const float* r1lb = (const float*)d_in[12];
  const float* r1ow = (const float*)d_in[13];
  const float* r1ob = (const float*)d_in[14];
  const float* r2pw = (const float*)d_in[15];
  const float* r2pb = (const float*)d_in[16];
  const float* r2lw = (const float*)d_in[17];
  const float* r2lb = (const float*)d_in[18];
  const float* r2ow = (const float*)d_in[19];
  const float* r2ob = (const float*)d_in[20];
  float* outp = (float*)d_out;

  char* ws = (char*)d_ws;
  size_t off = 0;
  auto carve = [&](size_t bytes) {
    char* p = ws + off;
    off += (bytes + 255) & ~(size_t)255;
    return p;
  };
  u16*   xn   = (u16*)carve((size_t)M_TOT * 384 * 2);
  u16*   u    = (u16*)carve((size_t)M_TOT * 768 * 2);
  u16*   vt   = (u16*)carve((size_t)768 * M_TOT * 2);
  u16*   cst  = (u16*)carve((size_t)768 * M_TOT * 2);
  u16*   Wuvt = (u16*)carve((size_t)1536 * 384 * 2);
  u16*   Wot  = (u16*)carve((size_t)384 * 768 * 2);
  float* aw_t = (float*)carve((size_t)128 * 768 * 4);
  float* ah_t = (float*)carve((size_t)128 * 768 * 4);
  u16*   g    = vt;  // alias: v_t dead after conv_k

  // RPE scratch aliased into cst region (cst written only later, by conv_k)
  char* rb  = (char*)cst;
  u16*   lwT = (u16*)rb;                               // 2*3*512*512*2 = 3 MB
  u16*   owT = (u16*)(rb + 3145728);                   // 2*768*512*2 = 1.5 MB
  float* X0  = (float*)(rb + 3145728 + 1572864);       // 256*512*4
  float* X1  = X0 + 256 * 512;

  prep_k<<<3456, 256, 0, stream>>>(Wu, Wv, Wo, Wuvt, Wot);
  rpet_k<<<2304, 256, 0, stream>>>(r1lw, r1ow, r2lw, r2ow, lwT, owT);
  rms_k<<<8192, 256, 0, stream>>>(x, xn);

  // RPE MLP chain (mlp0 = r1 -> a_w, mlp1 = r2 -> a_h)
  rpe_in_k<<<128, 256, 0, stream>>>(r1pw, r1pb, r2pw, r2pb, X0);
  rpe_layer_k<512><<<8, 256, 0, stream>>>(X0, lwT, lwT + 3 * 262144,
                                          r1lb, r2lb, X1, X1 + 128 * 512);
  rpe_layer_k<512><<<8, 256, 0, stream>>>(X1, lwT + 262144, lwT + 4 * 262144,
                                          r1lb + 512, r2lb + 512, X0, X0 + 128 * 512);
  rpe_layer_k<512><<<8, 256, 0, stream>>>(X0, lwT + 2 * 262144, lwT + 5 * 262144,
                                          r1lb + 1024, r2lb + 1024, X1, X1 + 128 * 512);
  rpe_layer_k<768><<<12, 256, 0, stream>>>(X1, owT, owT + 393216,
                                           r1ob, r2ob, aw_t, ah_t);

  // u|v GEMM: M=32768, N=1536, K=384
  gemm_k<0><<<256 * 12, 256, 0, stream>>>(xn, Wuvt, 384, 12,
                                          u, vt, bu, bv,
                                          nullptr, nullptr, nullptr);
  conv_k<<<8 * 6 * 64, 256, 0, stream>>>(vt, ah_t, aw_t, cst);
  transmul_k<<<512 * 12, 256, 0, stream>>>(cst, u, g);
  // out GEMM: M=32768, N=384, K=768 (+bo +x residual)
  gemm_k<1><<<256 * 3, 256, 0, stream>>>(g, Wot, 768, 3,
                                         nullptr, nullptr, nullptr, nullptr,
                                         outp, bo, x);
}

// Round 3
// 445.561 us; speedup vs baseline: 1.2738x; 1.1818x over previous
//
#include <hip/hip_runtime.h>
#include <stdint.h>

// ---------------------------------------------------------------------------
// GTU block: rmsnorm -> [u|v] GEMM+silu -> depthwise 2D circular Toeplitz conv
//            -> g = u*conv -> out = g@Wo + bo + x
// R3: (a) conv rewritten as MFMA (transposed-output trick: all operands
//     row-major); (b) GEMM LDS XOR-swizzle via pre-swizzled global source
//     (rule #21) killing the 16-way frag-read conflict; (c) fast silu;
//     (d) B-panel-major grid order (A re-reads land in L3).
// ---------------------------------------------------------------------------

typedef __attribute__((ext_vector_type(4))) float  f32x4;
typedef __attribute__((ext_vector_type(8))) short  s16x8;
typedef __attribute__((ext_vector_type(8))) unsigned short u16x8;
typedef __attribute__((ext_vector_type(4))) unsigned short u16x4;
typedef unsigned short u16;

#define M_TOT 32768      // B*H*W
#define E_DIM 384
#define D1    768
#define NHEAD 6
#define HDIM  128

__device__ __forceinline__ u16 f2bf(float f) {
  union { float f; unsigned int u; } v; v.f = f;
  unsigned int r = (v.u + 0x7FFFu + ((v.u >> 16) & 1u)) >> 16;
  return (u16)r;
}
__device__ __forceinline__ float bf2f(u16 h) {
  union { unsigned int u; float f; } v; v.u = ((unsigned int)h) << 16;
  return v.f;
}
// fast silu: x * rcp(1+exp(-x));  output goes to bf16, 1-ulp rcp/exp is plenty
__device__ __forceinline__ float silu_f(float x) {
  return x * __builtin_amdgcn_rcpf(1.f + __expf(-x));
}

__device__ __forceinline__ void gload_lds16(const u16* g, u16* l) {
  __builtin_amdgcn_global_load_lds(
      (const __attribute__((address_space(1))) uint32_t*)g,
      (__attribute__((address_space(3))) uint32_t*)l, 16, 0, 0);
}

// ---------------------------------------------------------------------------
// K1: main weight transpose + cast to bf16.
// ---------------------------------------------------------------------------
__global__ __launch_bounds__(256) void prep_k(const float* __restrict__ Wu,
                                              const float* __restrict__ Wv,
                                              const float* __restrict__ Wo,
                                              u16* __restrict__ Wuvt,
                                              u16* __restrict__ Wot) {
  int idx = blockIdx.x * 256 + threadIdx.x;
  const int NUV = 1536 * 384;
  if (idx < NUV) {
    int n = idx / 384, k = idx % 384;
    float val = (n < 768) ? Wu[(size_t)k * 768 + n] : Wv[(size_t)k * 768 + (n - 768)];
    Wuvt[idx] = f2bf(val);
  } else {
    int j = idx - NUV;
    if (j < 384 * 768) {
      int n = j / 768, k = j % 768;
      Wot[j] = f2bf(Wo[(size_t)k * 384 + n]);
    }
  }
}

// ---------------------------------------------------------------------------
// K1b: RPE weight transpose (tiled, coalesced both sides) fp32 -> bf16.
// ---------------------------------------------------------------------------
__global__ __launch_bounds__(256) void rpet_k(const float* __restrict__ r1lw,
                                              const float* __restrict__ r1ow,
                                              const float* __restrict__ r2lw,
                                              const float* __restrict__ r2ow,
                                              u16* __restrict__ lwT,
                                              u16* __restrict__ owT) {
  __shared__ float sm[32][33];
  int b = blockIdx.x;
  int mlp = b / 1152;
  int r = b % 1152;
  const float* src;
  u16* dst;
  int C, ty, tx;
  if (r < 768) {
    int L = r / 256, t = r % 256;
    ty = t / 16; tx = t % 16;
    src = (mlp ? r2lw : r1lw) + (size_t)L * 262144;
    dst = lwT + (size_t)(mlp * 3 + L) * 262144;
    C = 512;
  } else {
    int t = r - 768;
    ty = t / 24; tx = t % 24;
    src = mlp ? r2ow : r1ow;
    dst = owT + (size_t)mlp * 393216;
    C = 768;
  }
  int lx = threadIdx.x % 32, ly = threadIdx.x / 32;
#pragma unroll
  for (int q = 0; q < 4; q++) {
    int y = q * 8 + ly;
    sm[y][lx] = src[(size_t)(ty * 32 + y) * C + tx * 32 + lx];
  }
  __syncthreads();
#pragma unroll
  for (int q = 0; q < 4; q++) {
    int y = q * 8 + ly;
    dst[(size_t)(tx * 32 + y) * 512 + ty * 32 + lx] = f2bf(sm[lx][y]);
  }
}

// ---------------------------------------------------------------------------
// K2: SimpleRMSNorm rows of 384, write bf16.
// ---------------------------------------------------------------------------
__global__ __launch_bounds__(256) void rms_k(const float* __restrict__ x,
                                             u16* __restrict__ xn) {
  int row  = blockIdx.x * 4 + (threadIdx.x >> 6);
  int lane = threadIdx.x & 63;
  const float* xr = x + (size_t)row * 384 + lane;
  float v[6]; float ss = 0.f;
#pragma unroll
  for (int i = 0; i < 6; i++) { v[i] = xr[i * 64]; ss += v[i] * v[i]; }
#pragma unroll
  for (int off = 32; off > 0; off >>= 1) ss += __shfl_xor(ss, off);
  float sc = rsqrtf(ss * (1.f / 384.f) + 1e-6f);
  u16* o = xn + (size_t)row * 384 + lane;
#pragma unroll
  for (int i = 0; i < 6; i++) o[i * 64] = f2bf(v[i] * sc);
}

// ---------------------------------------------------------------------------
// K3a: RPE input layer
// ---------------------------------------------------------------------------
__global__ __launch_bounds__(256) void rpe_in_k(const float* __restrict__ r1pw,
                                                const float* __restrict__ r1pb,
                                                const float* __restrict__ r2pw,
                                                const float* __restrict__ r2pb,
                                                float* __restrict__ X0) {
  int idx = blockIdx.x * 256 + threadIdx.x;
  int gid = idx * 4;
  int row = gid >> 9, col = gid & 511;
  int mlp = row >> 7, p = row & 127;
  float pos = (p < 64) ? (float)p : ((p == 64) ? 0.f : (float)(p - 128));
  const float* pw = (mlp ? r2pw : r1pw) + col;
  const float* pb = (mlp ? r2pb : r1pb) + col;
  f32x4 w = *(const f32x4*)pw;
  f32x4 bb = *(const f32x4*)pb;
  f32x4 o;
#pragma unroll
  for (int e = 0; e < 4; e++) o[e] = fmaxf(pos * w[e] + bb[e], 0.f);
  *(f32x4*)(X0 + gid) = o;
}

// ---------------------------------------------------------------------------
// K3b: RPE layer GEMM (unchanged; ~tiny fraction of runtime)
// ---------------------------------------------------------------------------
template <int N>
__global__ __launch_bounds__(256) void rpe_layer_k(
    const float* __restrict__ X,
    const u16* __restrict__ wtA, const u16* __restrict__ wtB,
    const float* __restrict__ bA, const float* __restrict__ bB,
    float* __restrict__ outA, float* __restrict__ outB) {
  constexpr int NT = N / 128;
  const int mlp = blockIdx.x / NT;
  const int n0  = (blockIdx.x % NT) * 128;
  const u16* WT = mlp ? wtB : wtA;
  const float* bias = mlp ? bB : bA;
  float* out = mlp ? outB : outA;
  const float* Xm = X + (size_t)mlp * 128 * 512;

  __shared__ float scale[128];
  __shared__ __align__(16) u16 As[128 * 64];
  __shared__ __align__(16) u16 Bs[128 * 64];

  const int tid  = threadIdx.x;
  const int lane = tid & 63;
  const int wid  = tid >> 6;
  const int wm   = wid >> 1, wn = wid & 1;
  const int fl   = lane & 15, fh = lane >> 4;

  {
    int row = tid >> 1, half = tid & 1;
    const float* xr = Xm + (size_t)row * 512 + half * 256;
    float ss = 0.f;
#pragma unroll 8
    for (int q = 0; q < 64; q++) {
      f32x4 v = *(const f32x4*)(xr + q * 4);
      ss += v[0] * v[0] + v[1] * v[1] + v[2] * v[2] + v[3] * v[3];
    }
    ss += __shfl_xor(ss, 1);
    if (!half) scale[row] = rsqrtf(ss * (1.f / 512.f) + 1e-6f);
  }
  __syncthreads();

  f32x4 acc[4][4];
  {
    f32x4 z = {0.f, 0.f, 0.f, 0.f};
#pragma unroll
    for (int i = 0; i < 4; i++)
#pragma unroll
      for (int j = 0; j < 4; j++) acc[i][j] = z;
  }

  const int arow = tid >> 1, acb = (tid & 1) * 32;
  const int sr = tid >> 3, sc = (tid & 7) * 8;

  for (int kt = 0; kt < 512; kt += 64) {
    {
      const float* xp = Xm + (size_t)arow * 512 + kt + acb;
      float s_ = scale[arow];
      u16* dst = As + arow * 64 + acb;
#pragma unroll
      for (int q = 0; q < 8; q++) {
        f32x4 v = *(const f32x4*)(xp + q * 4);
        u16x4 pk;
#pragma unroll
        for (int e = 0; e < 4; e++) pk[e] = f2bf(fmaxf(v[e], 0.f) * s_);
        *(u16x4*)(dst + q * 4) = pk;
      }
    }
    {
      const u16* gB = WT + (size_t)(n0 + sr) * 512 + kt + sc;
      u16* lB = Bs + sr * 64 + sc;
#pragma unroll
      for (int i = 0; i < 4; i++)
        gload_lds16(gB + (size_t)(i * 32) * 512, lB + i * 32 * 64);
    }
    __syncthreads();
#pragma unroll
    for (int ks = 0; ks < 2; ks++) {
      s16x8 af[4], bfr[4];
      const u16* ap = As + (wm * 64 + fl) * 64 + ks * 32 + fh * 8;
      const u16* bp = Bs + (wn * 64 + fl) * 64 + ks * 32 + fh * 8;
#pragma unroll
      for (int i = 0; i < 4; i++) af[i] = *(const s16x8*)(ap + i * 16 * 64);
#pragma unroll
      for (int j = 0; j < 4; j++) bfr[j] = *(const s16x8*)(bp + j * 16 * 64);
#pragma unroll
      for (int i = 0; i < 4; i++)
#pragma unroll
        for (int j = 0; j < 4; j++)
          acc[i][j] = __builtin_amdgcn_mfma_f32_16x16x32_bf16(af[i], bfr[j], acc[i][j], 0, 0, 0);
    }
    __syncthreads();
  }

#pragma unroll
  for (int i = 0; i < 4; i++)
#pragma unroll
    for (int j = 0; j < 4; j++) {
      int c = n0 + wn * 64 + j * 16 + fl;
      float bv_ = bias[c];
#pragma unroll
      for (int q = 0; q < 4; q++) {
        int r = wm * 64 + i * 16 + fh * 4 + q;
        out[(size_t)r * N + c] = acc[i][j][q] + bv_;
      }
    }
}

// ---------------------------------------------------------------------------
// GEMM: C[m][n] = sum_k A[m][k]*Bt[n][k].  128x128 tile, BK=64, 4 waves,
// mfma 16x16x32 bf16.  LDS XOR-swizzled via pre-swizzled GLOBAL source
// (gload_lds dest stays linear); frag reads XOR chunk with (row&7).
// Grid: bm = bid&255 (B-panel-major: A re-reads hit L3, B stays L2-hot).
// ---------------------------------------------------------------------------
template <int MODE>
__global__ __launch_bounds__(256) void gemm_k(
    const u16* __restrict__ A, const u16* __restrict__ Bt, int K,
    u16* __restrict__ u_out, u16* __restrict__ vt_out,
    const float* __restrict__ bu, const float* __restrict__ bv,
    float* __restrict__ out, const float* __restrict__ bo,
    const float* __restrict__ xres) {
  __shared__ __align__(16) char smem[34816];
  u16*   As  = (u16*)smem;
  u16*   Bs  = As + 128 * 64;
  float* epi = (float*)smem;

  const int tid  = threadIdx.x;
  const int lane = tid & 63;
  const int wid  = tid >> 6;
  const int wm   = wid >> 1, wn = wid & 1;
  const int bm   = blockIdx.x & 255, bn = blockIdx.x >> 8;
  const int m0   = bm * 128, n0 = bn * 128;
  const int fl   = lane & 15, fh = lane >> 4;

  f32x4 acc[4][4];
  {
    f32x4 z = {0.f, 0.f, 0.f, 0.f};
#pragma unroll
    for (int i = 0; i < 4; i++)
#pragma unroll
      for (int j = 0; j < 4; j++) acc[i][j] = z;
  }

  const int sr  = tid >> 3;                          // staging row 0..31
  const int scl = (tid & 7) * 8;                     // linear LDS chunk
  const int scs = ((tid & 7) ^ (sr & 7)) * 8;        // swizzled global chunk

  for (int kt = 0; kt < K; kt += 64) {
    const u16* gA = A  + (size_t)(m0 + sr) * K + kt + scs;
    const u16* gB = Bt + (size_t)(n0 + sr) * K + kt + scs;
    u16* lA = As + sr * 64 + scl;
    u16* lB = Bs + sr * 64 + scl;
#pragma unroll
    for (int i = 0; i < 4; i++) {
      gload_lds16(gA + (size_t)(i * 32) * K, lA + i * 32 * 64);
      gload_lds16(gB + (size_t)(i * 32) * K, lB + i * 32 * 64);
    }
    __syncthreads();
#pragma unroll
    for (int ks = 0; ks < 2; ks++) {
      s16x8 af[4], bfr[4];
      const int xc = ((ks * 4 + fh) ^ (fl & 7)) * 8;   // swizzled read chunk
      const u16* ap = As + (wm * 64 + fl) * 64 + xc;
      const u16* bp = Bs + (wn * 64 + fl) * 64 + xc;
#pragma unroll
      for (int i = 0; i < 4; i++) af[i] = *(const s16x8*)(ap + i * 16 * 64);
#pragma unroll
      for (int j = 0; j < 4; j++) bfr[j] = *(const s16x8*)(bp + j * 16 * 64);
#pragma unroll
      for (int i = 0; i < 4; i++)
#pragma unroll
        for (int j = 0; j < 4; j++)
          acc[i][j] = __builtin_amdgcn_mfma_f32_16x16x32_bf16(af[i], bfr[j], acc[i][j], 0, 0, 0);
    }
    __syncthreads();
  }

  for (int half = 0; half < 2; half++) {
    __syncthreads();
    if (wm == half) {
#pragma unroll
      for (int i = 0; i < 4; i++)
#pragma unroll
        for (int j = 0; j < 4; j++) {
          int er = i * 16 + fh * 4;
          int ec = wn * 64 + j * 16 + fl;
#pragma unroll
          for (int q = 0; q < 4; q++) epi[(er + q) * 132 + ec] = acc[i][j][q];
        }
    }
    __syncthreads();
    if (MODE == 0) {
      if (n0 < 768) {
        int rr = tid >> 2;
        int gm = m0 + half * 64 + rr;
        u16* dst = u_out + (size_t)gm * 768 + n0;
#pragma unroll
        for (int q = 0; q < 4; q++) {
          int cb = (tid & 3) * 8 + q * 32;
          u16x8 pk;
#pragma unroll
          for (int e = 0; e < 8; e++) {
            int c = cb + e;
            pk[e] = f2bf(silu_f(epi[rr * 132 + c] + bu[n0 + c]));
          }
          *(u16x8*)(dst + cb) = pk;
        }
      } else {
        int cc = tid >> 1;
        int cg = n0 - 768 + cc;
        float bias = bv[cg];
        u16* dst = vt_out + (size_t)cg * M_TOT + m0 + half * 64;
#pragma unroll
        for (int q = 0; q < 4; q++) {
          int mb = (tid & 1) * 8 + q * 16;
          u16x8 pk;
#pragma unroll
          for (int e = 0; e < 8; e++) {
            int mm = mb + e;
            pk[e] = f2bf(silu_f(epi[mm * 132 + cc] + bias));
          }
          *(u16x8*)(dst + mb) = pk;
        }
      }
    } else {
      int rr = tid >> 2;
      int gm = m0 + half * 64 + rr;
      const float* xr = xres + (size_t)gm * 384 + n0;
      float* orow = out + (size_t)gm * 384 + n0;
#pragma unroll
      for (int q = 0; q < 8; q++) {
        int cb = (tid & 3) * 4 + q * 16;
        f32x4 xv = *(const f32x4*)(xr + cb);
        f32x4 ov;
#pragma unroll
        for (int e = 0; e < 4; e++) {
          int c = cb + e;
          ov[e] = epi[rr * 132 + c] + bo[n0 + c] + xv[e];
        }
        *(f32x4*)(orow + cb) = ov;
      }
    }
  }
}

// ---------------------------------------------------------------------------
// K5 (R3): MFMA Toeplitz conv.  Block = (channel c, batch b); computes the
// TRANSPOSED output  O^T[x][y] = sum_j VT[x][j]*Th[y][j] + Tw[x][j]*V[y][j]
// so ALL operand tiles are row-major in LDS (padded stride 72 -> conflict-
// free b128 frag reads).  Th[y][j]=ah_c[(y-j)&127], Tw[x][j]=aw_c[(x-j)&127].
// 4 waves, wave w owns y-tile w; acc[i] covers x-tile i.  64 MFMA/block.
// ---------------------------------------------------------------------------
__global__ __launch_bounds__(256) void conv_k(const u16* __restrict__ vt,
                                              const float* __restrict__ a_h,
                                              const float* __restrict__ a_w,
                                              u16* __restrict__ cst) {
  __shared__ __align__(16) char smraw[4 * 64 * 72 * 2 + 1024];
  u16* Vs  = (u16*)smraw;          // [64][72]  V[y][x]
  u16* VTs = Vs + 64 * 72;         // [64][72]  VT[x][y]
  u16* Ths = VTs + 64 * 72;        // [64][72]  (aliased by epi after compute)
  u16* Tws = Ths + 64 * 72;        // [64][72]
  float* ahs = (float*)(Tws + 64 * 72);   // [128]
  float* aws = ahs + 128;                 // [128]
  u16* epi = Ths;

  const int tid = threadIdx.x;
  const int c = blockIdx.x >> 3, b = blockIdx.x & 7;   // c-major: 8 b-blocks share coeffs
  const u16* src = vt + (size_t)c * M_TOT + b * 4096;

  // stage V (padded stride 72) + coeff tables
  {
    int y = tid >> 2, x0 = (tid & 3) * 16;
    u16x8 p0 = *(const u16x8*)(src + y * 64 + x0);
    u16x8 p1 = *(const u16x8*)(src + y * 64 + x0 + 8);
    *(u16x8*)(Vs + y * 72 + x0) = p0;
    *(u16x8*)(Vs + y * 72 + x0 + 8) = p1;
  }
  if (tid < 128) ahs[tid] = a_h[(size_t)tid * 768 + c];
  else           aws[tid - 128] = a_w[(size_t)(tid - 128) * 768 + c];
  __syncthreads();

  // build VT, Th, Tw
  {
    int y = tid & 63, j0 = (tid >> 6) * 16;
#pragma unroll
    for (int e = 0; e < 16; e++) {
      int j = j0 + e;
      VTs[j * 72 + y] = Vs[y * 72 + j];
      Ths[y * 72 + j] = f2bf(ahs[(y - j) & 127]);
      Tws[y * 72 + j] = f2bf(aws[(y - j) & 127]);
    }
  }
  __syncthreads();

  const int lane = tid & 63, w = tid >> 6;
  const int fl = lane & 15, fh = lane >> 4;
  f32x4 acc[4];
  {
    f32x4 z = {0.f, 0.f, 0.f, 0.f};
#pragma unroll
    for (int i = 0; i < 4; i++) acc[i] = z;
  }

#pragma unroll
  for (int ks = 0; ks < 2; ks++) {
    // H-part: D[x][y] += sum_j VT[x][j] * Th[y][j]
    s16x8 qh = *(const s16x8*)(Ths + (w * 16 + fl) * 72 + ks * 32 + fh * 8);
#pragma unroll
    for (int i = 0; i < 4; i++) {
      s16x8 p = *(const s16x8*)(VTs + (i * 16 + fl) * 72 + ks * 32 + fh * 8);
      acc[i] = __builtin_amdgcn_mfma_f32_16x16x32_bf16(p, qh, acc[i], 0, 0, 0);
    }
    // W-part: D[x][y] += sum_j Tw[x][j] * V[y][j]
    s16x8 qw = *(const s16x8*)(Vs + (w * 16 + fl) * 72 + ks * 32 + fh * 8);
#pragma unroll
    for (int i = 0; i < 4; i++) {
      s16x8 p = *(const s16x8*)(Tws + (i * 16 + fl) * 72 + ks * 32 + fh * 8);
      acc[i] = __builtin_amdgcn_mfma_f32_16x16x32_bf16(p, qw, acc[i], 0, 0, 0);
    }
  }
  __syncthreads();   // done reading Ths; epi aliases it

  // epi[y][x] <- acc (D[x][y]: x = i*16+fh*4+q, y = w*16+fl)
#pragma unroll
  for (int i = 0; i < 4; i++) {
    u16x4 pk;
#pragma unroll
    for (int e = 0; e < 4; e++) pk[e] = f2bf(acc[i][e]);
    *(u16x4*)(epi + (w * 16 + fl) * 72 + i * 16 + fh * 4) = pk;
  }
  __syncthreads();

  // coalesced store
  {
    int y = tid >> 2, x0 = (tid & 3) * 16;
    u16x8 a0 = *(const u16x8*)(epi + y * 72 + x0);
    u16x8 a1 = *(const u16x8*)(epi + y * 72 + x0 + 8);
    u16* dst = cst + (size_t)c * M_TOT + b * 4096 + y * 64 + x0;
    *(u16x8*)dst = a0;
    *(u16x8*)(dst + 8) = a1;
  }
}

// ---------------------------------------------------------------------------
// K6: g[m][c] = bf16( u[m][c] * cs_t[c][m] )
// ---------------------------------------------------------------------------
__global__ __launch_bounds__(256) void transmul_k(const u16* __restrict__ cst,
                                                  const u16* __restrict__ u,
                                                  u16* __restrict__ g) {
  __shared__ u16 ct[64 * 72];
  const int tid = threadIdx.x;
  int bm = blockIdx.x / 12, bc = blockIdx.x % 12;
  int m0 = bm * 64, c0 = bc * 64;
  {
    int cc = tid >> 2, sg = (tid & 3) * 8;
    const u16* src = cst + (size_t)(c0 + cc) * M_TOT + m0 + sg;
    *(u16x8*)(ct + cc * 72 + sg)      = *(const u16x8*)(src);
    *(u16x8*)(ct + cc * 72 + sg + 32) = *(const u16x8*)(src + 32);
  }
  __syncthreads();
  int mr = tid >> 2;
  int gm = m0 + mr;
  const u16* up = u + (size_t)gm * 768 + c0;
  u16* gp = g + (size_t)gm * 768 + c0;
#pragma unroll
  for (int q = 0; q < 2; q++) {
    int cb = (tid & 3) * 8 + q * 32;
    u16x8 uv = *(const u16x8*)(up + cb);
    u16x8 pk;
#pragma unroll
    for (int e = 0; e < 8; e++) {
      int c = cb + e;
      pk[e] = f2bf(bf2f(uv[e]) * bf2f(ct[c * 72 + mr]));
    }
    *(u16x8*)(gp + cb) = pk;
  }
}

// ---------------------------------------------------------------------------
extern "C" void kernel_launch(void* const* d_in, const int* in_sizes, int n_in,
                              void* d_out, int out_size, void* d_ws, size_t ws_size,
                              hipStream_t stream) {
  const float* x    = (const float*)d_in[0];
  const float* Wu   = (const float*)d_in[3];
  const float* bu   = (const float*)d_in[4];
  const float* Wv   = (const float*)d_in[5];
  const float* bv   = (const float*)d_in[6];
  const float* Wo   = (const float*)d_in[7];
  const float* bo   = (const float*)d_in[8];
  const float* r1pw = (const float*)d_in[9];
  const float* r1pb = (const float*)d_in[10];
  const float* r1lw = (const float*)d_in[11];
  const float* r1lb = (const float*)d_in[12];
  const float* r1ow = (const float*)d_in[13];
  const float* r1ob = (const float*)d_in[14];
  const float* r2pw = (const float*)d_in[15];
  const float* r2pb = (const float*)d_in[16];
  const float* r2lw = (const float*)d_in[17];
  const float* r2lb = (const float*)d_in[18];
  const float* r2ow = (const float*)d_in[19];
  const float* r2ob = (const float*)d_in[20];
  float* outp = (float*)d_out;

  char* ws = (char*)d_ws;
  size_t off = 0;
  auto carve = [&](size_t bytes) {
    char* p = ws + off;
    off += (bytes + 255) & ~(size_t)255;
    return p;
  };
  u16*   xn   = (u16*)carve((size_t)M_TOT * 384 * 2);
  u16*   u    = (u16*)carve((size_t)M_TOT * 768 * 2);
  u16*   vt   = (u16*)carve((size_t)768 * M_TOT * 2);
  u16*   cst  = (u16*)carve((size_t)768 * M_TOT * 2);
  u16*   Wuvt = (u16*)carve((size_t)1536 * 384 * 2);
  u16*   Wot  = (u16*)carve((size_t)384 * 768 * 2);
  float* aw_t = (float*)carve((size_t)128 * 768 * 4);
  float* ah_t = (float*)carve((size_t)128 * 768 * 4);
  u16*   g    = vt;  // alias: v_t dead after conv_k

  // RPE scratch aliased into cst region (cst written only later, by conv_k)
  char* rb  = (char*)cst;
  u16*   lwT = (u16*)rb;
  u16*   owT = (u16*)(rb + 3145728);
  float* X0  = (float*)(rb + 3145728 + 1572864);
  float* X1  = X0 + 256 * 512;

  prep_k<<<3456, 256, 0, stream>>>(Wu, Wv, Wo, Wuvt, Wot);
  rpet_k<<<2304, 256, 0, stream>>>(r1lw, r1ow, r2lw, r2ow, lwT, owT);
  rms_k<<<8192, 256, 0, stream>>>(x, xn);

  rpe_in_k<<<128, 256, 0, stream>>>(r1pw, r1pb, r2pw, r2pb, X0);
  rpe_layer_k<512><<<8, 256, 0, stream>>>(X0, lwT, lwT + 3 * 262144,
                                          r1lb, r2lb, X1, X1 + 128 * 512);
  rpe_layer_k<512><<<8, 256, 0, stream>>>(X1, lwT + 262144, lwT + 4 * 262144,
                                          r1lb + 512, r2lb + 512, X0, X0 + 128 * 512);
  rpe_layer_k<512><<<8, 256, 0, stream>>>(X0, lwT + 2 * 262144, lwT + 5 * 262144,
                                          r1lb + 1024, r2lb + 1024, X1, X1 + 128 * 512);
  rpe_layer_k<768><<<12, 256, 0, stream>>>(X1, owT, owT + 393216,
                                           r1ob, r2ob, aw_t, ah_t);

  // u|v GEMM: M=32768, N=1536, K=384  (grid: bm = bid&255, bn = bid>>8)
  gemm_k<0><<<256 * 12, 256, 0, stream>>>(xn, Wuvt, 384,
                                          u, vt, bu, bv,
                                          nullptr, nullptr, nullptr);
  conv_k<<<768 * 8, 256, 0, stream>>>(vt, ah_t, aw_t, cst);
  transmul_k<<<512 * 12, 256, 0, stream>>>(cst, u, g);
  // out GEMM: M=32768, N=384, K=768 (+bo +x residual)
  gemm_k<1><<<256 * 3, 256, 0, stream>>>(g, Wot, 768,
                                         nullptr, nullptr, nullptr, nullptr,
                                         outp, bo, x);
}

// Round 4
// 432.443 us; speedup vs baseline: 1.3124x; 1.0303x over previous
//
#include <hip/hip_runtime.h>
#include <stdint.h>

// ---------------------------------------------------------------------------
// GTU block: rmsnorm -> [u|v] GEMM+silu -> depthwise 2D circular Toeplitz conv
//            -> gate -> out = g@Wo + bo + x
// R4: (a) transmul_k eliminated: gemm<0> emits uT+vT, conv applies the u-gate
//     in its fp32 epilogue and writes gT; gemm<1> stages A from gT via a
//     conflict-free c-major LDS-transpose scatter into the swizzled As.
//     (b) setup kernels merged into one blockIdx-partitioned setup_k with
//     fully tiled/coalesced weight transposes.  (c) RPE coeffs stored (C,P)
//     so conv's coefficient loads are contiguous.  8 graph nodes (was 12).
// ---------------------------------------------------------------------------

typedef __attribute__((ext_vector_type(4))) float  f32x4;
typedef __attribute__((ext_vector_type(8))) short  s16x8;
typedef __attribute__((ext_vector_type(8))) unsigned short u16x8;
typedef __attribute__((ext_vector_type(4))) unsigned short u16x4;
typedef unsigned short u16;

#define M_TOT 32768      // B*H*W
#define E_DIM 384
#define D1    768

__device__ __forceinline__ u16 f2bf(float f) {
  union { float f; unsigned int u; } v; v.f = f;
  unsigned int r = (v.u + 0x7FFFu + ((v.u >> 16) & 1u)) >> 16;
  return (u16)r;
}
__device__ __forceinline__ float bf2f(u16 h) {
  union { unsigned int u; float f; } v; v.u = ((unsigned int)h) << 16;
  return v.f;
}
__device__ __forceinline__ float silu_f(float x) {
  return x * __builtin_amdgcn_rcpf(1.f + __expf(-x));
}

__device__ __forceinline__ void gload_lds16(const u16* g, u16* l) {
  __builtin_amdgcn_global_load_lds(
      (const __attribute__((address_space(1))) uint32_t*)g,
      (__attribute__((address_space(3))) uint32_t*)l, 16, 0, 0);
}

// ---------------------------------------------------------------------------
// setup_k: blockIdx-partitioned fusion of
//   [0,8192)      rmsnorm rows (x -> xn bf16)
//   [8192,11360)  tiled fp32->bf16 transposes (rpe lw/ow, Wu, Wv, Wo)
//   [11360,11488) rpe input layer X0 = relu(pos*pw+pb)
// ---------------------------------------------------------------------------
__global__ __launch_bounds__(256) void setup_k(
    const float* __restrict__ x, u16* __restrict__ xn,
    const float* __restrict__ Wu, const float* __restrict__ Wv,
    const float* __restrict__ Wo, u16* __restrict__ Wuvt, u16* __restrict__ Wot,
    const float* __restrict__ r1lw, const float* __restrict__ r1ow,
    const float* __restrict__ r2lw, const float* __restrict__ r2ow,
    u16* __restrict__ lwT, u16* __restrict__ owT,
    const float* __restrict__ r1pw, const float* __restrict__ r1pb,
    const float* __restrict__ r2pw, const float* __restrict__ r2pb,
    float* __restrict__ X0) {
  __shared__ float sm[32][33];
  const int bid = blockIdx.x;
  const int tid = threadIdx.x;

  if (bid < 8192) {                     // ---- rmsnorm ----
    int row  = bid * 4 + (tid >> 6);
    int lane = tid & 63;
    const float* xr = x + (size_t)row * 384 + lane;
    float v[6]; float ss = 0.f;
#pragma unroll
    for (int i = 0; i < 6; i++) { v[i] = xr[i * 64]; ss += v[i] * v[i]; }
#pragma unroll
    for (int off = 32; off > 0; off >>= 1) ss += __shfl_xor(ss, off);
    float sc = rsqrtf(ss * (1.f / 384.f) + 1e-6f);
    u16* o = xn + (size_t)row * 384 + lane;
#pragma unroll
    for (int i = 0; i < 6; i++) o[i * 64] = f2bf(v[i] * sc);
  } else if (bid < 11360) {             // ---- tiled transposes ----
    int b = bid - 8192;
    const float* src; u16* dst; int C, DS, R0, C0;
    if (b < 2304) {
      int mlp = b / 1152, r = b % 1152;
      if (r < 768) {
        int L = r / 256, t = r % 256;
        R0 = (t / 16) * 32; C0 = (t % 16) * 32;
        src = (mlp ? r2lw : r1lw) + (size_t)L * 262144;
        dst = lwT + (size_t)(mlp * 3 + L) * 262144;
        C = 512; DS = 512;
      } else {
        int t = r - 768;
        R0 = (t / 24) * 32; C0 = (t % 24) * 32;
        src = mlp ? r2ow : r1ow;
        dst = owT + (size_t)mlp * 393216;
        C = 768; DS = 512;
      }
    } else {
      int t = b - 2304;
      if (t < 288)      { R0 = (t / 24) * 32; C0 = (t % 24) * 32;
                          src = Wu; C = 768; dst = Wuvt;            DS = 384; }
      else if (t < 576) { int t2 = t - 288; R0 = (t2 / 24) * 32; C0 = (t2 % 24) * 32;
                          src = Wv; C = 768; dst = Wuvt + 768 * 384; DS = 384; }
      else              { int t2 = t - 576; R0 = (t2 / 12) * 32; C0 = (t2 % 12) * 32;
                          src = Wo; C = 384; dst = Wot;             DS = 768; }
    }
    int lx = tid % 32, ly = tid / 32;
#pragma unroll
    for (int q = 0; q < 4; q++) {
      int y = q * 8 + ly;
      sm[y][lx] = src[(size_t)(R0 + y) * C + C0 + lx];
    }
    __syncthreads();
#pragma unroll
    for (int q = 0; q < 4; q++) {
      int y = q * 8 + ly;
      dst[(size_t)(C0 + y) * DS + R0 + lx] = f2bf(sm[lx][y]);
    }
  } else {                              // ---- rpe input layer ----
    int idx = (bid - 11360) * 256 + tid;
    int gid = idx * 4;
    int row = gid >> 9, col = gid & 511;
    int mlp = row >> 7, p = row & 127;
    float pos = (p < 64) ? (float)p : ((p == 64) ? 0.f : (float)(p - 128));
    const float* pw = (mlp ? r2pw : r1pw) + col;
    const float* pb = (mlp ? r2pb : r1pb) + col;
    f32x4 w = *(const f32x4*)pw;
    f32x4 bb = *(const f32x4*)pb;
    f32x4 o;
#pragma unroll
    for (int e = 0; e < 4; e++) o[e] = fmaxf(pos * w[e] + bb[e], 0.f);
    *(f32x4*)(X0 + gid) = o;
  }
}

// ---------------------------------------------------------------------------
// RPE layer GEMM.  X (256x512 fp32) -> relu(srms(X)) @ WT^T + bias.
// TOUT=true (final layer): store transposed (C,128) for conv's coalesced load.
// ---------------------------------------------------------------------------
template <int N, bool TOUT>
__global__ __launch_bounds__(256) void rpe_layer_k(
    const float* __restrict__ X,
    const u16* __restrict__ wtA, const u16* __restrict__ wtB,
    const float* __restrict__ bA, const float* __restrict__ bB,
    float* __restrict__ outA, float* __restrict__ outB) {
  constexpr int NT = N / 128;
  const int mlp = blockIdx.x / NT;
  const int n0  = (blockIdx.x % NT) * 128;
  const u16* WT = mlp ? wtB : wtA;
  const float* bias = mlp ? bB : bA;
  float* out = mlp ? outB : outA;
  const float* Xm = X + (size_t)mlp * 128 * 512;

  __shared__ float scale[128];
  __shared__ __align__(16) u16 As[128 * 64];
  __shared__ __align__(16) u16 Bs[128 * 64];

  const int tid  = threadIdx.x;
  const int lane = tid & 63;
  const int wid  = tid >> 6;
  const int wm   = wid >> 1, wn = wid & 1;
  const int fl   = lane & 15, fh = lane >> 4;

  {
    int row = tid >> 1, half = tid & 1;
    const float* xr = Xm + (size_t)row * 512 + half * 256;
    float ss = 0.f;
#pragma unroll 8
    for (int q = 0; q < 64; q++) {
      f32x4 v = *(const f32x4*)(xr + q * 4);
      ss += v[0] * v[0] + v[1] * v[1] + v[2] * v[2] + v[3] * v[3];
    }
    ss += __shfl_xor(ss, 1);
    if (!half) scale[row] = rsqrtf(ss * (1.f / 512.f) + 1e-6f);
  }
  __syncthreads();

  f32x4 acc[4][4];
  {
    f32x4 z = {0.f, 0.f, 0.f, 0.f};
#pragma unroll
    for (int i = 0; i < 4; i++)
#pragma unroll
      for (int j = 0; j < 4; j++) acc[i][j] = z;
  }

  const int arow = tid >> 1, acb = (tid & 1) * 32;
  const int sr = tid >> 3, sc = (tid & 7) * 8;

  for (int kt = 0; kt < 512; kt += 64) {
    {
      const float* xp = Xm + (size_t)arow * 512 + kt + acb;
      float s_ = scale[arow];
      u16* dst = As + arow * 64 + acb;
#pragma unroll
      for (int q = 0; q < 8; q++) {
        f32x4 v = *(const f32x4*)(xp + q * 4);
        u16x4 pk;
#pragma unroll
        for (int e = 0; e < 4; e++) pk[e] = f2bf(fmaxf(v[e], 0.f) * s_);
        *(u16x4*)(dst + q * 4) = pk;
      }
    }
    {
      const u16* gB = WT + (size_t)(n0 + sr) * 512 + kt + sc;
      u16* lB = Bs + sr * 64 + sc;
#pragma unroll
      for (int i = 0; i < 4; i++)
        gload_lds16(gB + (size_t)(i * 32) * 512, lB + i * 32 * 64);
    }
    __syncthreads();
#pragma unroll
    for (int ks = 0; ks < 2; ks++) {
      s16x8 af[4], bfr[4];
      const u16* ap = As + (wm * 64 + fl) * 64 + ks * 32 + fh * 8;
      const u16* bp = Bs + (wn * 64 + fl) * 64 + ks * 32 + fh * 8;
#pragma unroll
      for (int i = 0; i < 4; i++) af[i] = *(const s16x8*)(ap + i * 16 * 64);
#pragma unroll
      for (int j = 0; j < 4; j++) bfr[j] = *(const s16x8*)(bp + j * 16 * 64);
#pragma unroll
      for (int i = 0; i < 4; i++)
#pragma unroll
        for (int j = 0; j < 4; j++)
          acc[i][j] = __builtin_amdgcn_mfma_f32_16x16x32_bf16(af[i], bfr[j], acc[i][j], 0, 0, 0);
    }
    __syncthreads();
  }

#pragma unroll
  for (int i = 0; i < 4; i++)
#pragma unroll
    for (int j = 0; j < 4; j++) {
      int c = n0 + wn * 64 + j * 16 + fl;
      float bv_ = bias[c];
#pragma unroll
      for (int q = 0; q < 4; q++) {
        int r = wm * 64 + i * 16 + fh * 4 + q;
        if (TOUT) out[(size_t)c * 128 + r] = acc[i][j][q] + bv_;
        else      out[(size_t)r * N + c]   = acc[i][j][q] + bv_;
      }
    }
}

// ---------------------------------------------------------------------------
// Main GEMM.  C[m][n] = sum_k A[m][k]*Bt[n][k]; 128x128 tile, BK=64, 4 waves,
// mfma 16x16x32 bf16, XOR-swizzled LDS (pre-swizzled global source for
// gload_lds paths; matching swizzled scatter for the MODE-1 gT transpose).
// MODE 0: A=xn (M,384); out silu(C+bias) -> uT (n<768) / vT, both (C,M).
// MODE 1: A=gT (C,M) -- staged via conflict-free c-major scatter transpose;
//         out = C + bo + x -> fp32 (M,384).
// ---------------------------------------------------------------------------
template <int MODE>
__global__ __launch_bounds__(256) void gemm_k(
    const u16* __restrict__ A, const u16* __restrict__ Bt, int K,
    u16* __restrict__ u_out, u16* __restrict__ vt_out,
    const float* __restrict__ bu, const float* __restrict__ bv,
    float* __restrict__ out, const float* __restrict__ bo,
    const float* __restrict__ xres) {
  __shared__ __align__(16) char smem[34816];
  u16*   As  = (u16*)smem;
  u16*   Bs  = As + 128 * 64;
  float* epi = (float*)smem;

  const int tid  = threadIdx.x;
  const int lane = tid & 63;
  const int wid  = tid >> 6;
  const int wm   = wid >> 1, wn = wid & 1;
  const int bm   = blockIdx.x & 255, bn = blockIdx.x >> 8;
  const int m0   = bm * 128, n0 = bn * 128;
  const int fl   = lane & 15, fh = lane >> 4;

  f32x4 acc[4][4];
  {
    f32x4 z = {0.f, 0.f, 0.f, 0.f};
#pragma unroll
    for (int i = 0; i < 4; i++)
#pragma unroll
      for (int j = 0; j < 4; j++) acc[i][j] = z;
  }

  const int sr  = tid >> 3;                          // staging row 0..31
  const int scl = (tid & 7) * 8;                     // linear LDS chunk
  const int scs = ((tid & 7) ^ (sr & 7)) * 8;        // swizzled global chunk
  const int cr  = tid & 63;                          // MODE1: k-row in tile
  const int mw  = ((tid >> 6) & 3) * 32;             // MODE1: m-window

  for (int kt = 0; kt < K; kt += 64) {
    if (MODE == 1) {
      // A from gT (C,M): coalesced-ish row reads, conflict-free swizzled
      // scatter transpose into As (per step all lanes share m -> 32 dwords).
      const u16* ga = A + (size_t)(kt + cr) * M_TOT + m0 + mw;
      u16x8 rr[4];
      rr[0] = *(const u16x8*)(ga);
      rr[1] = *(const u16x8*)(ga + 8);
      rr[2] = *(const u16x8*)(ga + 16);
      rr[3] = *(const u16x8*)(ga + 24);
      const int cb8 = cr >> 3, off = cr & 7;
#pragma unroll
      for (int v = 0; v < 4; v++)
#pragma unroll
        for (int e = 0; e < 8; e++)
          As[(mw + v * 8 + e) * 64 + ((cb8 ^ e) << 3) + off] = rr[v][e];
    } else {
      const u16* gA = A + (size_t)(m0 + sr) * K + kt + scs;
      u16* lA = As + sr * 64 + scl;
#pragma unroll
      for (int i = 0; i < 4; i++)
        gload_lds16(gA + (size_t)(i * 32) * K, lA + i * 32 * 64);
    }
    {
      const u16* gB = Bt + (size_t)(n0 + sr) * K + kt + scs;
      u16* lB = Bs + sr * 64 + scl;
#pragma unroll
      for (int i = 0; i < 4; i++)
        gload_lds16(gB + (size_t)(i * 32) * K, lB + i * 32 * 64);
    }
    __syncthreads();
#pragma unroll
    for (int ks = 0; ks < 2; ks++) {
      s16x8 af[4], bfr[4];
      const int xc = ((ks * 4 + fh) ^ (fl & 7)) * 8;   // swizzled read chunk
      const u16* ap = As + (wm * 64 + fl) * 64 + xc;
      const u16* bp = Bs + (wn * 64 + fl) * 64 + xc;
#pragma unroll
      for (int i = 0; i < 4; i++) af[i] = *(const s16x8*)(ap + i * 16 * 64);
#pragma unroll
      for (int j = 0; j < 4; j++) bfr[j] = *(const s16x8*)(bp + j * 16 * 64);
#pragma unroll
      for (int i = 0; i < 4; i++)
#pragma unroll
        for (int j = 0; j < 4; j++)
          acc[i][j] = __builtin_amdgcn_mfma_f32_16x16x32_bf16(af[i], bfr[j], acc[i][j], 0, 0, 0);
    }
    __syncthreads();
  }

  for (int half = 0; half < 2; half++) {
    __syncthreads();
    if (wm == half) {
#pragma unroll
      for (int i = 0; i < 4; i++)
#pragma unroll
        for (int j = 0; j < 4; j++) {
          int er = i * 16 + fh * 4;
          int ec = wn * 64 + j * 16 + fl;
#pragma unroll
          for (int q = 0; q < 4; q++) epi[(er + q) * 132 + ec] = acc[i][j][q];
        }
    }
    __syncthreads();
    if (MODE == 0) {
      const bool isU = (n0 < 768);
      u16* baseo = isU ? u_out : vt_out;
      const int cc = tid >> 1;
      const int cg = (isU ? n0 : n0 - 768) + cc;
      const float bias_v = (isU ? bu : bv)[cg];
      u16* dst = baseo + (size_t)cg * M_TOT + m0 + half * 64;
#pragma unroll
      for (int q = 0; q < 4; q++) {
        int mb = (tid & 1) * 8 + q * 16;
        u16x8 pk;
#pragma unroll
        for (int e = 0; e < 8; e++) {
          int mm = mb + e;
          pk[e] = f2bf(silu_f(epi[mm * 132 + cc] + bias_v));
        }
        *(u16x8*)(dst + mb) = pk;
      }
    } else {
      int rr = tid >> 2;
      int gm = m0 + half * 64 + rr;
      const float* xr = xres + (size_t)gm * 384 + n0;
      float* orow = out + (size_t)gm * 384 + n0;
#pragma unroll
      for (int q = 0; q < 8; q++) {
        int cb = (tid & 3) * 4 + q * 16;
        f32x4 xv = *(const f32x4*)(xr + cb);
        f32x4 ov;
#pragma unroll
        for (int e = 0; e < 4; e++) {
          int c = cb + e;
          ov[e] = epi[rr * 132 + c] + bo[n0 + c] + xv[e];
        }
        *(f32x4*)(orow + cb) = ov;
      }
    }
  }
}

// ---------------------------------------------------------------------------
// conv_k: MFMA Toeplitz conv + u-gate.  Block = (channel c, batch b).
// O^T[x][y] = sum_j VT[x][j]*Th[y][j] + Tw[x][j]*V[y][j]; all tiles row-major
// (stride 72).  Epilogue: gT[c][m] = bf16( uT[c][m] * O[m] )  (fp32 gate).
// Coeffs read from transposed (C,128) tables -> contiguous loads.
// ---------------------------------------------------------------------------
__global__ __launch_bounds__(256) void conv_k(const u16* __restrict__ vt,
                                              const u16* __restrict__ ut,
                                              const float* __restrict__ a_hT,
                                              const float* __restrict__ a_wT,
                                              u16* __restrict__ gT) {
  __shared__ __align__(16) char smraw[5 * 64 * 72 * 2 + 1024];
  u16* Vs  = (u16*)smraw;          // [64][72]  V[y][x]
  u16* VTs = Vs + 64 * 72;         // [64][72]  VT[x][y]
  u16* Ths = VTs + 64 * 72;        // [64][72]  (aliased by epi after MFMA)
  u16* Tws = Ths + 64 * 72;        // [64][72]
  u16* Us  = Tws + 64 * 72;        // [64][72]  u[y][x]
  float* ahs = (float*)(Us + 64 * 72);   // [128]
  float* aws = ahs + 128;                // [128]
  u16* epi = Ths;

  const int tid = threadIdx.x;
  const int c = blockIdx.x >> 3, b = blockIdx.x & 7;
  const u16* srcv = vt + (size_t)c * M_TOT + b * 4096;
  const u16* srcu = ut + (size_t)c * M_TOT + b * 4096;

  {
    int y = tid >> 2, x0 = (tid & 3) * 16;
    *(u16x8*)(Vs + y * 72 + x0)     = *(const u16x8*)(srcv + y * 64 + x0);
    *(u16x8*)(Vs + y * 72 + x0 + 8) = *(const u16x8*)(srcv + y * 64 + x0 + 8);
    *(u16x8*)(Us + y * 72 + x0)     = *(const u16x8*)(srcu + y * 64 + x0);
    *(u16x8*)(Us + y * 72 + x0 + 8) = *(const u16x8*)(srcu + y * 64 + x0 + 8);
  }
  if (tid < 128) ahs[tid] = a_hT[(size_t)c * 128 + tid];
  else           aws[tid - 128] = a_wT[(size_t)c * 128 + (tid - 128)];
  __syncthreads();

  {
    int y = tid & 63, j0 = (tid >> 6) * 16;
#pragma unroll
    for (int e = 0; e < 16; e++) {
      int j = j0 + e;
      VTs[j * 72 + y] = Vs[y * 72 + j];
      Ths[y * 72 + j] = f2bf(ahs[(y - j) & 127]);
      Tws[y * 72 + j] = f2bf(aws[(y - j) & 127]);
    }
  }
  __syncthreads();

  const int lane = tid & 63, w = tid >> 6;
  const int fl = lane & 15, fh = lane >> 4;
  f32x4 acc[4];
  {
    f32x4 z = {0.f, 0.f, 0.f, 0.f};
#pragma unroll
    for (int i = 0; i < 4; i++) acc[i] = z;
  }

#pragma unroll
  for (int ks = 0; ks < 2; ks++) {
    s16x8 qh = *(const s16x8*)(Ths + (w * 16 + fl) * 72 + ks * 32 + fh * 8);
#pragma unroll
    for (int i = 0; i < 4; i++) {
      s16x8 p = *(const s16x8*)(VTs + (i * 16 + fl) * 72 + ks * 32 + fh * 8);
      acc[i] = __builtin_amdgcn_mfma_f32_16x16x32_bf16(p, qh, acc[i], 0, 0, 0);
    }
    s16x8 qw = *(const s16x8*)(Vs + (w * 16 + fl) * 72 + ks * 32 + fh * 8);
#pragma unroll
    for (int i = 0; i < 4; i++) {
      s16x8 p = *(const s16x8*)(Tws + (i * 16 + fl) * 72 + ks * 32 + fh * 8);
      acc[i] = __builtin_amdgcn_mfma_f32_16x16x32_bf16(p, qw, acc[i], 0, 0, 0);
    }
  }
  __syncthreads();   // done reading Ths; epi aliases it

  // gate + pack: epi[y][x] = bf16( u[y][x] * O^T[x][y] )
  {
    int y = w * 16 + fl;
#pragma unroll
    for (int i = 0; i < 4; i++) {
      u16x4 pk;
#pragma unroll
      for (int e = 0; e < 4; e++) {
        int xx = i * 16 + fh * 4 + e;
        pk[e] = f2bf(acc[i][e] * bf2f(Us[y * 72 + xx]));
      }
      *(u16x4*)(epi + y * 72 + i * 16 + fh * 4) = pk;
    }
  }
  __syncthreads();

  {
    int y = tid >> 2, x0 = (tid & 3) * 16;
    u16x8 a0 = *(const u16x8*)(epi + y * 72 + x0);
    u16x8 a1 = *(const u16x8*)(epi + y * 72 + x0 + 8);
    u16* dst = gT + (size_t)c * M_TOT + b * 4096 + y * 64 + x0;
    *(u16x8*)dst = a0;
    *(u16x8*)(dst + 8) = a1;
  }
}

// ---------------------------------------------------------------------------
extern "C" void kernel_launch(void* const* d_in, const int* in_sizes, int n_in,
                              void* d_out, int out_size, void* d_ws, size_t ws_size,
                              hipStream_t stream) {
  const float* x    = (const float*)d_in[0];
  const float* Wu   = (const float*)d_in[3];
  const float* bu   = (const float*)d_in[4];
  const float* Wv   = (const float*)d_in[5];
  const float* bv   = (const float*)d_in[6];
  const float* Wo   = (const float*)d_in[7];
  const float* bo   = (const float*)d_in[8];
  const float* r1pw = (const float*)d_in[9];
  const float* r1pb = (const float*)d_in[10];
  const float* r1lw = (const float*)d_in[11];
  const float* r1lb = (const float*)d_in[12];
  const float* r1ow = (const float*)d_in[13];
  const float* r1ob = (const float*)d_in[14];
  const float* r2pw = (const float*)d_in[15];
  const float* r2pb = (const float*)d_in[16];
  const float* r2lw = (const float*)d_in[17];
  const float* r2lb = (const float*)d_in[18];
  const float* r2ow = (const float*)d_in[19];
  const float* r2ob = (const float*)d_in[20];
  float* outp = (float*)d_out;

  char* ws = (char*)d_ws;
  size_t off = 0;
  auto carve = [&](size_t bytes) {
    char* p = ws + off;
    off += (bytes + 255) & ~(size_t)255;
    return p;
  };
  u16*   xn   = (u16*)carve((size_t)M_TOT * 384 * 2);
  u16*   uT   = (u16*)carve((size_t)768 * M_TOT * 2);
  u16*   vT   = (u16*)carve((size_t)768 * M_TOT * 2);
  u16*   gT   = (u16*)carve((size_t)768 * M_TOT * 2);
  u16*   Wuvt = (u16*)carve((size_t)1536 * 384 * 2);
  u16*   Wot  = (u16*)carve((size_t)384 * 768 * 2);
  float* awT  = (float*)carve((size_t)768 * 128 * 4);
  float* ahT  = (float*)carve((size_t)768 * 128 * 4);

  // RPE scratch aliased into gT region (gT written only later, by conv_k)
  char* rb  = (char*)gT;
  u16*   lwT = (u16*)rb;                               // 2*3*512*512*2 = 3 MB
  u16*   owT = (u16*)(rb + 3145728);                   // 2*768*512*2 = 1.5 MB
  float* X0  = (float*)(rb + 3145728 + 1572864);       // 256*512*4
  float* X1  = X0 + 256 * 512;

  setup_k<<<11488, 256, 0, stream>>>(x, xn, Wu, Wv, Wo, Wuvt, Wot,
                                     r1lw, r1ow, r2lw, r2ow, lwT, owT,
                                     r1pw, r1pb, r2pw, r2pb, X0);

  rpe_layer_k<512, false><<<8, 256, 0, stream>>>(X0, lwT, lwT + 3 * 262144,
                                                 r1lb, r2lb, X1, X1 + 128 * 512);
  rpe_layer_k<512, false><<<8, 256, 0, stream>>>(X1, lwT + 262144, lwT + 4 * 262144,
                                                 r1lb + 512, r2lb + 512, X0, X0 + 128 * 512);
  rpe_layer_k<512, false><<<8, 256, 0, stream>>>(X0, lwT + 2 * 262144, lwT + 5 * 262144,
                                                 r1lb + 1024, r2lb + 1024, X1, X1 + 128 * 512);
  rpe_layer_k<768, true><<<12, 256, 0, stream>>>(X1, owT, owT + 393216,
                                                 r1ob, r2ob, awT, ahT);

  // u|v GEMM: M=32768, N=1536, K=384 -> uT, vT (both (C,M))
  gemm_k<0><<<256 * 12, 256, 0, stream>>>(xn, Wuvt, 384,
                                          uT, vT, bu, bv,
                                          nullptr, nullptr, nullptr);
  // conv + gate -> gT (C,M)
  conv_k<<<768 * 8, 256, 0, stream>>>(vT, uT, ahT, awT, gT);
  // out GEMM: M=32768, N=384, K=768 (A = gT via transpose staging) + bo + x
  gemm_k<1><<<256 * 3, 256, 0, stream>>>(gT, Wot, 768,
                                         nullptr, nullptr, nullptr, nullptr,
                                         outp, bo, x);
}

// Round 5
// 395.927 us; speedup vs baseline: 1.4335x; 1.0922x over previous
//
#include <hip/hip_runtime.h>
#include <stdint.h>

// ---------------------------------------------------------------------------
// GTU block: rmsnorm -> [u|v] GEMM+silu -> depthwise 2D circular Toeplitz conv
//            -> gate -> out = g@Wo + bo + x
// R5: (a) conv_k: block=channel, 8-batch loop, Th/Tw built ONCE via reversed
//     doubled coeff buffer (contiguous-in-j -> vectorized build), vectorized
//     VT build + gate.  (b) gemm2_k (out-proj): 128x384 tile, 512 thr, A
//     scatter-transpose runs once per A-tile (was 3x), direct epilogue.
// ---------------------------------------------------------------------------

typedef __attribute__((ext_vector_type(4))) float  f32x4;
typedef __attribute__((ext_vector_type(8))) short  s16x8;
typedef __attribute__((ext_vector_type(8))) unsigned short u16x8;
typedef __attribute__((ext_vector_type(4))) unsigned short u16x4;
typedef unsigned short u16;

#define M_TOT 32768      // B*H*W

__device__ __forceinline__ u16 f2bf(float f) {
  union { float f; unsigned int u; } v; v.f = f;
  unsigned int r = (v.u + 0x7FFFu + ((v.u >> 16) & 1u)) >> 16;
  return (u16)r;
}
__device__ __forceinline__ float bf2f(u16 h) {
  union { unsigned int u; float f; } v; v.u = ((unsigned int)h) << 16;
  return v.f;
}
__device__ __forceinline__ float silu_f(float x) {
  return x * __builtin_amdgcn_rcpf(1.f + __expf(-x));
}

__device__ __forceinline__ void gload_lds16(const u16* g, u16* l) {
  __builtin_amdgcn_global_load_lds(
      (const __attribute__((address_space(1))) uint32_t*)g,
      (__attribute__((address_space(3))) uint32_t*)l, 16, 0, 0);
}

// ---------------------------------------------------------------------------
// setup_k: blockIdx-partitioned fusion (rmsnorm | weight transposes | rpe-in)
// ---------------------------------------------------------------------------
__global__ __launch_bounds__(256) void setup_k(
    const float* __restrict__ x, u16* __restrict__ xn,
    const float* __restrict__ Wu, const float* __restrict__ Wv,
    const float* __restrict__ Wo, u16* __restrict__ Wuvt, u16* __restrict__ Wot,
    const float* __restrict__ r1lw, const float* __restrict__ r1ow,
    const float* __restrict__ r2lw, const float* __restrict__ r2ow,
    u16* __restrict__ lwT, u16* __restrict__ owT,
    const float* __restrict__ r1pw, const float* __restrict__ r1pb,
    const float* __restrict__ r2pw, const float* __restrict__ r2pb,
    float* __restrict__ X0) {
  __shared__ float sm[32][33];
  const int bid = blockIdx.x;
  const int tid = threadIdx.x;

  if (bid < 8192) {                     // ---- rmsnorm ----
    int row  = bid * 4 + (tid >> 6);
    int lane = tid & 63;
    const float* xr = x + (size_t)row * 384 + lane;
    float v[6]; float ss = 0.f;
#pragma unroll
    for (int i = 0; i < 6; i++) { v[i] = xr[i * 64]; ss += v[i] * v[i]; }
#pragma unroll
    for (int off = 32; off > 0; off >>= 1) ss += __shfl_xor(ss, off);
    float sc = rsqrtf(ss * (1.f / 384.f) + 1e-6f);
    u16* o = xn + (size_t)row * 384 + lane;
#pragma unroll
    for (int i = 0; i < 6; i++) o[i * 64] = f2bf(v[i] * sc);
  } else if (bid < 11360) {             // ---- tiled transposes ----
    int b = bid - 8192;
    const float* src; u16* dst; int C, DS, R0, C0;
    if (b < 2304) {
      int mlp = b / 1152, r = b % 1152;
      if (r < 768) {
        int L = r / 256, t = r % 256;
        R0 = (t / 16) * 32; C0 = (t % 16) * 32;
        src = (mlp ? r2lw : r1lw) + (size_t)L * 262144;
        dst = lwT + (size_t)(mlp * 3 + L) * 262144;
        C = 512; DS = 512;
      } else {
        int t = r - 768;
        R0 = (t / 24) * 32; C0 = (t % 24) * 32;
        src = mlp ? r2ow : r1ow;
        dst = owT + (size_t)mlp * 393216;
        C = 768; DS = 512;
      }
    } else {
      int t = b - 2304;
      if (t < 288)      { R0 = (t / 24) * 32; C0 = (t % 24) * 32;
                          src = Wu; C = 768; dst = Wuvt;             DS = 384; }
      else if (t < 576) { int t2 = t - 288; R0 = (t2 / 24) * 32; C0 = (t2 % 24) * 32;
                          src = Wv; C = 768; dst = Wuvt + 768 * 384; DS = 384; }
      else              { int t2 = t - 576; R0 = (t2 / 12) * 32; C0 = (t2 % 12) * 32;
                          src = Wo; C = 384; dst = Wot;              DS = 768; }
    }
    int lx = tid % 32, ly = tid / 32;
#pragma unroll
    for (int q = 0; q < 4; q++) {
      int y = q * 8 + ly;
      sm[y][lx] = src[(size_t)(R0 + y) * C + C0 + lx];
    }
    __syncthreads();
#pragma unroll
    for (int q = 0; q < 4; q++) {
      int y = q * 8 + ly;
      dst[(size_t)(C0 + y) * DS + R0 + lx] = f2bf(sm[lx][y]);
    }
  } else {                              // ---- rpe input layer ----
    int idx = (bid - 11360) * 256 + tid;
    int gid = idx * 4;
    int row = gid >> 9, col = gid & 511;
    int mlp = row >> 7, p = row & 127;
    float pos = (p < 64) ? (float)p : ((p == 64) ? 0.f : (float)(p - 128));
    const float* pw = (mlp ? r2pw : r1pw) + col;
    const float* pb = (mlp ? r2pb : r1pb) + col;
    f32x4 w = *(const f32x4*)pw;
    f32x4 bb = *(const f32x4*)pb;
    f32x4 o;
#pragma unroll
    for (int e = 0; e < 4; e++) o[e] = fmaxf(pos * w[e] + bb[e], 0.f);
    *(f32x4*)(X0 + gid) = o;
  }
}

// ---------------------------------------------------------------------------
// RPE layer GEMM.  TOUT=true: store transposed (C,128) for conv.
// ---------------------------------------------------------------------------
template <int N, bool TOUT>
__global__ __launch_bounds__(256) void rpe_layer_k(
    const float* __restrict__ X,
    const u16* __restrict__ wtA, const u16* __restrict__ wtB,
    const float* __restrict__ bA, const float* __restrict__ bB,
    float* __restrict__ outA, float* __restrict__ outB) {
  constexpr int NT = N / 128;
  const int mlp = blockIdx.x / NT;
  const int n0  = (blockIdx.x % NT) * 128;
  const u16* WT = mlp ? wtB : wtA;
  const float* bias = mlp ? bB : bA;
  float* out = mlp ? outB : outA;
  const float* Xm = X + (size_t)mlp * 128 * 512;

  __shared__ float scale[128];
  __shared__ __align__(16) u16 As[128 * 64];
  __shared__ __align__(16) u16 Bs[128 * 64];

  const int tid  = threadIdx.x;
  const int lane = tid & 63;
  const int wid  = tid >> 6;
  const int wm   = wid >> 1, wn = wid & 1;
  const int fl   = lane & 15, fh = lane >> 4;

  {
    int row = tid >> 1, half = tid & 1;
    const float* xr = Xm + (size_t)row * 512 + half * 256;
    float ss = 0.f;
#pragma unroll 8
    for (int q = 0; q < 64; q++) {
      f32x4 v = *(const f32x4*)(xr + q * 4);
      ss += v[0] * v[0] + v[1] * v[1] + v[2] * v[2] + v[3] * v[3];
    }
    ss += __shfl_xor(ss, 1);
    if (!half) scale[row] = rsqrtf(ss * (1.f / 512.f) + 1e-6f);
  }
  __syncthreads();

  f32x4 acc[4][4];
  {
    f32x4 z = {0.f, 0.f, 0.f, 0.f};
#pragma unroll
    for (int i = 0; i < 4; i++)
#pragma unroll
      for (int j = 0; j < 4; j++) acc[i][j] = z;
  }

  const int arow = tid >> 1, acb = (tid & 1) * 32;
  const int sr = tid >> 3, sc = (tid & 7) * 8;

  for (int kt = 0; kt < 512; kt += 64) {
    {
      const float* xp = Xm + (size_t)arow * 512 + kt + acb;
      float s_ = scale[arow];
      u16* dst = As + arow * 64 + acb;
#pragma unroll
      for (int q = 0; q < 8; q++) {
        f32x4 v = *(const f32x4*)(xp + q * 4);
        u16x4 pk;
#pragma unroll
        for (int e = 0; e < 4; e++) pk[e] = f2bf(fmaxf(v[e], 0.f) * s_);
        *(u16x4*)(dst + q * 4) = pk;
      }
    }
    {
      const u16* gB = WT + (size_t)(n0 + sr) * 512 + kt + sc;
      u16* lB = Bs + sr * 64 + sc;
#pragma unroll
      for (int i = 0; i < 4; i++)
        gload_lds16(gB + (size_t)(i * 32) * 512, lB + i * 32 * 64);
    }
    __syncthreads();
#pragma unroll
    for (int ks = 0; ks < 2; ks++) {
      s16x8 af[4], bfr[4];
      const u16* ap = As + (wm * 64 + fl) * 64 + ks * 32 + fh * 8;
      const u16* bp = Bs + (wn * 64 + fl) * 64 + ks * 32 + fh * 8;
#pragma unroll
      for (int i = 0; i < 4; i++) af[i] = *(const s16x8*)(ap + i * 16 * 64);
#pragma unroll
      for (int j = 0; j < 4; j++) bfr[j] = *(const s16x8*)(bp + j * 16 * 64);
#pragma unroll
      for (int i = 0; i < 4; i++)
#pragma unroll
        for (int j = 0; j < 4; j++)
          acc[i][j] = __builtin_amdgcn_mfma_f32_16x16x32_bf16(af[i], bfr[j], acc[i][j], 0, 0, 0);
    }
    __syncthreads();
  }

#pragma unroll
  for (int i = 0; i < 4; i++)
#pragma unroll
    for (int j = 0; j < 4; j++) {
      int c = n0 + wn * 64 + j * 16 + fl;
      float bv_ = bias[c];
#pragma unroll
      for (int q = 0; q < 4; q++) {
        int r = wm * 64 + i * 16 + fh * 4 + q;
        if (TOUT) out[(size_t)c * 128 + r] = acc[i][j][q] + bv_;
        else      out[(size_t)r * N + c]   = acc[i][j][q] + bv_;
      }
    }
}

// ---------------------------------------------------------------------------
// gemm0_k: [u|v] projection.  C[m][n] = sum_k xn[m][k]*Wuvt[n][k].
// 128x128 tile, BK=64, 4 waves, XOR-swizzled LDS (pre-swizzled global src).
// Epilogue: silu(C+bias) -> uT (n<768) / vT (n>=768), both (C,M) transposed.
// ---------------------------------------------------------------------------
__global__ __launch_bounds__(256) void gemm0_k(
    const u16* __restrict__ A, const u16* __restrict__ Bt,
    u16* __restrict__ u_out, u16* __restrict__ vt_out,
    const float* __restrict__ bu, const float* __restrict__ bv) {
  __shared__ __align__(16) char smem[34816];
  u16*   As  = (u16*)smem;
  u16*   Bs  = As + 128 * 64;
  float* epi = (float*)smem;

  const int tid  = threadIdx.x;
  const int lane = tid & 63;
  const int wid  = tid >> 6;
  const int wm   = wid >> 1, wn = wid & 1;
  const int bm   = blockIdx.x & 255, bn = blockIdx.x >> 8;
  const int m0   = bm * 128, n0 = bn * 128;
  const int fl   = lane & 15, fh = lane >> 4;
  const int K    = 384;

  f32x4 acc[4][4];
  {
    f32x4 z = {0.f, 0.f, 0.f, 0.f};
#pragma unroll
    for (int i = 0; i < 4; i++)
#pragma unroll
      for (int j = 0; j < 4; j++) acc[i][j] = z;
  }

  const int sr  = tid >> 3;
  const int scl = (tid & 7) * 8;
  const int scs = ((tid & 7) ^ (sr & 7)) * 8;

  for (int kt = 0; kt < K; kt += 64) {
    const u16* gA = A  + (size_t)(m0 + sr) * K + kt + scs;
    const u16* gB = Bt + (size_t)(n0 + sr) * K + kt + scs;
    u16* lA = As + sr * 64 + scl;
    u16* lB = Bs + sr * 64 + scl;
#pragma unroll
    for (int i = 0; i < 4; i++) {
      gload_lds16(gA + (size_t)(i * 32) * K, lA + i * 32 * 64);
      gload_lds16(gB + (size_t)(i * 32) * K, lB + i * 32 * 64);
    }
    __syncthreads();
#pragma unroll
    for (int ks = 0; ks < 2; ks++) {
      s16x8 af[4], bfr[4];
      const int xc = ((ks * 4 + fh) ^ (fl & 7)) * 8;
      const u16* ap = As + (wm * 64 + fl) * 64 + xc;
      const u16* bp = Bs + (wn * 64 + fl) * 64 + xc;
#pragma unroll
      for (int i = 0; i < 4; i++) af[i] = *(const s16x8*)(ap + i * 16 * 64);
#pragma unroll
      for (int j = 0; j < 4; j++) bfr[j] = *(const s16x8*)(bp + j * 16 * 64);
#pragma unroll
      for (int i = 0; i < 4; i++)
#pragma unroll
        for (int j = 0; j < 4; j++)
          acc[i][j] = __builtin_amdgcn_mfma_f32_16x16x32_bf16(af[i], bfr[j], acc[i][j], 0, 0, 0);
    }
    __syncthreads();
  }

  for (int half = 0; half < 2; half++) {
    __syncthreads();
    if (wm == half) {
#pragma unroll
      for (int i = 0; i < 4; i++)
#pragma unroll
        for (int j = 0; j < 4; j++) {
          int er = i * 16 + fh * 4;
          int ec = wn * 64 + j * 16 + fl;
#pragma unroll
          for (int q = 0; q < 4; q++) epi[(er + q) * 132 + ec] = acc[i][j][q];
        }
    }
    __syncthreads();
    const bool isU = (n0 < 768);
    u16* baseo = isU ? u_out : vt_out;
    const int cc = tid >> 1;
    const int cg = (isU ? n0 : n0 - 768) + cc;
    const float bias_v = (isU ? bu : bv)[cg];
    u16* dst = baseo + (size_t)cg * M_TOT + m0 + half * 64;
#pragma unroll
    for (int q = 0; q < 4; q++) {
      int mb = (tid & 1) * 8 + q * 16;
      u16x8 pk;
#pragma unroll
      for (int e = 0; e < 8; e++) {
        int mm = mb + e;
        pk[e] = f2bf(silu_f(epi[mm * 132 + cc] + bias_v));
      }
      *(u16x8*)(dst + mb) = pk;
    }
  }
}

// ---------------------------------------------------------------------------
// gemm2_k: out[m][n] = sum_k gT[k][m]*Wot[n][k] + bo[n] + x[m][n].
// Tile 128(M) x 384(N=full), BK=64, 512 threads (8 waves: 2m x 4n).
// A staged from k-major gT via conflict-free swizzled scatter (once per
// A-tile, amortized over all 384 N).  B via gload_lds.  Direct epilogue.
// ---------------------------------------------------------------------------
__global__ __launch_bounds__(512, 2) void gemm2_k(
    const u16* __restrict__ gT, const u16* __restrict__ Wot,
    float* __restrict__ out, const float* __restrict__ bo,
    const float* __restrict__ xres) {
  __shared__ __align__(16) u16 As[128 * 64];   // 16 KB, swizzled
  __shared__ __align__(16) u16 Bs[384 * 64];   // 48 KB, swizzled

  const int tid  = threadIdx.x;
  const int lane = tid & 63;
  const int wid  = tid >> 6;        // 0..7
  const int wm   = wid >> 2;        // 0..1
  const int wn   = wid & 3;         // 0..3
  const int m0   = blockIdx.x * 128;
  const int fl   = lane & 15, fh = lane >> 4;

  f32x4 acc[4][6];
  {
    f32x4 z = {0.f, 0.f, 0.f, 0.f};
#pragma unroll
    for (int i = 0; i < 4; i++)
#pragma unroll
      for (int j = 0; j < 6; j++) acc[i][j] = z;
  }

  const int sr  = tid >> 3;                    // 0..63 (B staging row)
  const int scl = (tid & 7) * 8;
  const int scs = ((tid & 7) ^ (sr & 7)) * 8;
  const int cr  = tid & 63;                    // A: k-row
  const int mw  = (tid >> 6) * 16;             // A: m-window
  const int c8  = cr >> 3, of = cr & 7;

  for (int kt = 0; kt < 768; kt += 64) {
    // B: 6 x gload_lds (384 rows x 64 k)
#pragma unroll
    for (int i = 0; i < 6; i++)
      gload_lds16(Wot + (size_t)(sr + 64 * i) * 768 + kt + scs,
                  Bs + (sr + 64 * i) * 64 + scl);
    // A: 16 m-contig bf16 from gT row (kt+cr), swizzled scatter transpose
    {
      const u16* ga = gT + (size_t)(kt + cr) * M_TOT + m0 + mw;
      u16x8 r0 = *(const u16x8*)ga;
      u16x8 r1 = *(const u16x8*)(ga + 8);
#pragma unroll
      for (int e = 0; e < 8; e++)
        As[(mw + e) * 64 + ((c8 ^ e) << 3) + of] = r0[e];
#pragma unroll
      for (int e = 0; e < 8; e++)
        As[(mw + 8 + e) * 64 + ((c8 ^ e) << 3) + of] = r1[e];
    }
    __syncthreads();
#pragma unroll
    for (int ks = 0; ks < 2; ks++) {
      s16x8 af[4], bfr[6];
      const int xc = ((ks * 4 + fh) ^ (fl & 7)) * 8;
      const u16* ap = As + (wm * 64 + fl) * 64 + xc;
      const u16* bp = Bs + (wn * 96 + fl) * 64 + xc;
#pragma unroll
      for (int i = 0; i < 4; i++) af[i] = *(const s16x8*)(ap + i * 16 * 64);
#pragma unroll
      for (int j = 0; j < 6; j++) bfr[j] = *(const s16x8*)(bp + j * 16 * 64);
#pragma unroll
      for (int i = 0; i < 4; i++)
#pragma unroll
        for (int j = 0; j < 6; j++)
          acc[i][j] = __builtin_amdgcn_mfma_f32_16x16x32_bf16(af[i], bfr[j], acc[i][j], 0, 0, 0);
    }
    __syncthreads();
  }

  // direct epilogue: + bo + x, fp32 stores (4x64B segments per instr)
  float bov[6];
#pragma unroll
  for (int j = 0; j < 6; j++) bov[j] = bo[wn * 96 + j * 16 + fl];
#pragma unroll
  for (int i = 0; i < 4; i++) {
#pragma unroll
    for (int q = 0; q < 4; q++) {
      int m = m0 + wm * 64 + i * 16 + fh * 4 + q;
      const float* xr = xres + (size_t)m * 384;
      float* orow = out + (size_t)m * 384;
#pragma unroll
      for (int j = 0; j < 6; j++) {
        int n = wn * 96 + j * 16 + fl;
        orow[n] = acc[i][j][q] + bov[j] + xr[n];
      }
    }
  }
}

// ---------------------------------------------------------------------------
// conv_k: MFMA Toeplitz conv + u-gate.  Block = channel c (grid 768),
// loops b=0..7.  Th/Tw built ONCE per block from reversed doubled coeff
// buffers (Th[y][j]=ahr[128-y+j], contiguous in j -> vectorized build).
// O^T[x][y] = sum_j VT[x][j]*Th[y][j] + Tw[x][j]*V[y][j]; row-major tiles
// (stride 72, conflict-free).  Epilogue: gT[c][m] = bf16(uT[c][m]*O[m]).
// ---------------------------------------------------------------------------
__global__ __launch_bounds__(256) void conv_k(const u16* __restrict__ vt,
                                              const u16* __restrict__ ut,
                                              const float* __restrict__ a_hT,
                                              const float* __restrict__ a_wT,
                                              u16* __restrict__ gT) {
  __shared__ __align__(16) u16 Th[64 * 72];
  __shared__ __align__(16) u16 Tw[64 * 72];
  __shared__ __align__(16) u16 Vs[64 * 72];
  __shared__ __align__(16) u16 VTs[64 * 72];
  __shared__ __align__(16) u16 Us[64 * 72];
  __shared__ float ahr[192];
  __shared__ float awr[192];
  u16* epi = VTs;   // alias: VTs dead after MFMA within each b-iteration

  const int tid = threadIdx.x;
  const int c = blockIdx.x;
  const int lane = tid & 63, w = tid >> 6;
  const int fl = lane & 15, fh = lane >> 4;

  // ---- coeff staging (reversed): ahr[t] = ah_c[(128-t)&127] ----
  if (tid < 192) {
    int idx = (128 - tid) & 127;
    ahr[tid] = a_hT[(size_t)c * 128 + idx];
    awr[tid] = a_wT[(size_t)c * 128 + idx];
  }
  __syncthreads();

  // ---- build Th/Tw once: Th[y][j] = ahr[128-y+j], contiguous in j ----
  {
    int y = tid & 63, j0 = (tid >> 6) * 16;
    int base = 128 - y + j0;
    u16x8 p0, p1, q0, q1;
#pragma unroll
    for (int e = 0; e < 8; e++) {
      p0[e] = f2bf(ahr[base + e]);
      p1[e] = f2bf(ahr[base + 8 + e]);
      q0[e] = f2bf(awr[base + e]);
      q1[e] = f2bf(awr[base + 8 + e]);
    }
    *(u16x8*)(Th + y * 72 + j0)     = p0;
    *(u16x8*)(Th + y * 72 + j0 + 8) = p1;
    *(u16x8*)(Tw + y * 72 + j0)     = q0;
    *(u16x8*)(Tw + y * 72 + j0 + 8) = q1;
  }

  const int sy = tid >> 2, sx = (tid & 3) * 16;      // stage/store coords
  const int ty = tid & 63, tj = (tid >> 6) * 16;     // VT-build coords

  for (int b = 0; b < 8; b++) {
    const u16* srcv = vt + (size_t)c * M_TOT + b * 4096;
    const u16* srcu = ut + (size_t)c * M_TOT + b * 4096;
    // stage V, U (padded stride 72)
    *(u16x8*)(Vs + sy * 72 + sx)     = *(const u16x8*)(srcv + sy * 64 + sx);
    *(u16x8*)(Vs + sy * 72 + sx + 8) = *(const u16x8*)(srcv + sy * 64 + sx + 8);
    *(u16x8*)(Us + sy * 72 + sx)     = *(const u16x8*)(srcu + sy * 64 + sx);
    *(u16x8*)(Us + sy * 72 + sx + 8) = *(const u16x8*)(srcu + sy * 64 + sx + 8);
    __syncthreads();   // V ready (also covers Th/Tw build on b==0)

    // build VT (vector reads, contiguous-lane scalar writes)
    {
      u16x8 q0 = *(const u16x8*)(Vs + ty * 72 + tj);
      u16x8 q1 = *(const u16x8*)(Vs + ty * 72 + tj + 8);
#pragma unroll
      for (int e = 0; e < 8; e++) VTs[(tj + e) * 72 + ty]     = q0[e];
#pragma unroll
      for (int e = 0; e < 8; e++) VTs[(tj + 8 + e) * 72 + ty] = q1[e];
    }
    __syncthreads();

    f32x4 acc[4];
    {
      f32x4 z = {0.f, 0.f, 0.f, 0.f};
#pragma unroll
      for (int i = 0; i < 4; i++) acc[i] = z;
    }
#pragma unroll
    for (int ks = 0; ks < 2; ks++) {
      s16x8 qh = *(const s16x8*)(Th + (w * 16 + fl) * 72 + ks * 32 + fh * 8);
#pragma unroll
      for (int i = 0; i < 4; i++) {
        s16x8 p = *(const s16x8*)(VTs + (i * 16 + fl) * 72 + ks * 32 + fh * 8);
        acc[i] = __builtin_amdgcn_mfma_f32_16x16x32_bf16(p, qh, acc[i], 0, 0, 0);
      }
      s16x8 qw = *(const s16x8*)(Vs + (w * 16 + fl) * 72 + ks * 32 + fh * 8);
#pragma unroll
      for (int i = 0; i < 4; i++) {
        s16x8 p = *(const s16x8*)(Tw + (i * 16 + fl) * 72 + ks * 32 + fh * 8);
        acc[i] = __builtin_amdgcn_mfma_f32_16x16x32_bf16(p, qw, acc[i], 0, 0, 0);
      }
    }
    __syncthreads();   // all reads of VTs done; epi may overwrite

    // gate + pack: epi[y][x] = bf16( u[y][x] * O^T[x][y] )
    {
      int y = w * 16 + fl;
#pragma unroll
      for (int i = 0; i < 4; i++) {
        u16x4 uq = *(const u16x4*)(Us + y * 72 + i * 16 + fh * 4);
        u16x4 pk;
#pragma unroll
        for (int e = 0; e < 4; e++) pk[e] = f2bf(acc[i][e] * bf2f(uq[e]));
        *(u16x4*)(epi + y * 72 + i * 16 + fh * 4) = pk;
      }
    }
    __syncthreads();

    // coalesced store
    {
      u16x8 a0 = *(const u16x8*)(epi + sy * 72 + sx);
      u16x8 a1 = *(const u16x8*)(epi + sy * 72 + sx + 8);
      u16* dst = gT + (size_t)c * M_TOT + b * 4096 + sy * 64 + sx;
      *(u16x8*)dst = a0;
      *(u16x8*)(dst + 8) = a1;
    }
    __syncthreads();   // before next-b staging clobbers Vs/Us/epi
  }
}

// ---------------------------------------------------------------------------
extern "C" void kernel_launch(void* const* d_in, const int* in_sizes, int n_in,
                              void* d_out, int out_size, void* d_ws, size_t ws_size,
                              hipStream_t stream) {
  const float* x    = (const float*)d_in[0];
  const float* Wu   = (const float*)d_in[3];
  const float* bu   = (const float*)d_in[4];
  const float* Wv   = (const float*)d_in[5];
  const float* bv   = (const float*)d_in[6];
  const float* Wo   = (const float*)d_in[7];
  const float* bo   = (const float*)d_in[8];
  const float* r1pw = (const float*)d_in[9];
  const float* r1pb = (const float*)d_in[10];
  const float* r1lw = (const float*)d_in[11];
  const float* r1lb = (const float*)d_in[12];
  const float* r1ow = (const float*)d_in[13];
  const float* r1ob = (const float*)d_in[14];
  const float* r2pw = (const float*)d_in[15];
  const float* r2pb = (const float*)d_in[16];
  const float* r2lw = (const float*)d_in[17];
  const float* r2lb = (const float*)d_in[18];
  const float* r2ow = (const float*)d_in[19];
  const float* r2ob = (const float*)d_in[20];
  float* outp = (float*)d_out;

  char* ws = (char*)d_ws;
  size_t off = 0;
  auto carve = [&](size_t bytes) {
    char* p = ws + off;
    off += (bytes + 255) & ~(size_t)255;
    return p;
  };
  u16*   xn   = (u16*)carve((size_t)M_TOT * 384 * 2);
  u16*   uT   = (u16*)carve((size_t)768 * M_TOT * 2);
  u16*   vT   = (u16*)carve((size_t)768 * M_TOT * 2);
  u16*   gT   = (u16*)carve((size_t)768 * M_TOT * 2);
  u16*   Wuvt = (u16*)carve((size_t)1536 * 384 * 2);
  u16*   Wot  = (u16*)carve((size_t)384 * 768 * 2);
  float* awT  = (float*)carve((size_t)768 * 128 * 4);
  float* ahT  = (float*)carve((size_t)768 * 128 * 4);

  // RPE scratch aliased into gT region (gT written only later, by conv_k)
  char* rb  = (char*)gT;
  u16*   lwT = (u16*)rb;                               // 3 MB
  u16*   owT = (u16*)(rb + 3145728);                   // 1.5 MB
  float* X0  = (float*)(rb + 3145728 + 1572864);
  float* X1  = X0 + 256 * 512;

  setup_k<<<11488, 256, 0, stream>>>(x, xn, Wu, Wv, Wo, Wuvt, Wot,
                                     r1lw, r1ow, r2lw, r2ow, lwT, owT,
                                     r1pw, r1pb, r2pw, r2pb, X0);

  rpe_layer_k<512, false><<<8, 256, 0, stream>>>(X0, lwT, lwT + 3 * 262144,
                                                 r1lb, r2lb, X1, X1 + 128 * 512);
  rpe_layer_k<512, false><<<8, 256, 0, stream>>>(X1, lwT + 262144, lwT + 4 * 262144,
                                                 r1lb + 512, r2lb + 512, X0, X0 + 128 * 512);
  rpe_layer_k<512, false><<<8, 256, 0, stream>>>(X0, lwT + 2 * 262144, lwT + 5 * 262144,
                                                 r1lb + 1024, r2lb + 1024, X1, X1 + 128 * 512);
  rpe_layer_k<768, true><<<12, 256, 0, stream>>>(X1, owT, owT + 393216,
                                                 r1ob, r2ob, awT, ahT);

  // u|v GEMM: M=32768, N=1536, K=384 -> uT, vT (both (C,M))
  gemm0_k<<<256 * 12, 256, 0, stream>>>(xn, Wuvt, uT, vT, bu, bv);
  // conv + gate -> gT (C,M); block = channel
  conv_k<<<768, 256, 0, stream>>>(vT, uT, ahT, awT, gT);
  // out GEMM: M=32768, N=384(full), K=768 (+bo +x residual)
  gemm2_k<<<256, 512, 0, stream>>>(gT, Wot, outp, bo, x);
}

// Round 6
// 366.272 us; speedup vs baseline: 1.5495x; 1.0810x over previous
//
#include <hip/hip_runtime.h>
#include <stdint.h>

// ---------------------------------------------------------------------------
// GTU block: rmsnorm -> [u|v] GEMM+silu -> depthwise 2D circular Toeplitz conv
//            -> gate -> out = g@Wo + bo + x
// R6: (a) rpe_layer_k redesigned: B-slice fully LDS-resident (one up-front
//     global_load_lds burst), dbuf+reg-prefetch A path, XOR-swizzled LDS both
//     operands, grid 2x(N/64) -> latency ~halved per layer.
//     (b) gemm2_k A staging remapped to coalesced 256B row-runs.
// ---------------------------------------------------------------------------

typedef __attribute__((ext_vector_type(4))) float  f32x4;
typedef __attribute__((ext_vector_type(8))) short  s16x8;
typedef __attribute__((ext_vector_type(8))) unsigned short u16x8;
typedef __attribute__((ext_vector_type(4))) unsigned short u16x4;
typedef unsigned short u16;

#define M_TOT 32768      // B*H*W

__device__ __forceinline__ u16 f2bf(float f) {
  union { float f; unsigned int u; } v; v.f = f;
  unsigned int r = (v.u + 0x7FFFu + ((v.u >> 16) & 1u)) >> 16;
  return (u16)r;
}
__device__ __forceinline__ float bf2f(u16 h) {
  union { unsigned int u; float f; } v; v.u = ((unsigned int)h) << 16;
  return v.f;
}
__device__ __forceinline__ float silu_f(float x) {
  return x * __builtin_amdgcn_rcpf(1.f + __expf(-x));
}

__device__ __forceinline__ void gload_lds16(const u16* g, u16* l) {
  __builtin_amdgcn_global_load_lds(
      (const __attribute__((address_space(1))) uint32_t*)g,
      (__attribute__((address_space(3))) uint32_t*)l, 16, 0, 0);
}

// ---------------------------------------------------------------------------
// setup_k: blockIdx-partitioned fusion (rmsnorm | weight transposes | rpe-in)
// ---------------------------------------------------------------------------
__global__ __launch_bounds__(256) void setup_k(
    const float* __restrict__ x, u16* __restrict__ xn,
    const float* __restrict__ Wu, const float* __restrict__ Wv,
    const float* __restrict__ Wo, u16* __restrict__ Wuvt, u16* __restrict__ Wot,
    const float* __restrict__ r1lw, const float* __restrict__ r1ow,
    const float* __restrict__ r2lw, const float* __restrict__ r2ow,
    u16* __restrict__ lwT, u16* __restrict__ owT,
    const float* __restrict__ r1pw, const float* __restrict__ r1pb,
    const float* __restrict__ r2pw, const float* __restrict__ r2pb,
    float* __restrict__ X0) {
  __shared__ float sm[32][33];
  const int bid = blockIdx.x;
  const int tid = threadIdx.x;

  if (bid < 8192) {                     // ---- rmsnorm ----
    int row  = bid * 4 + (tid >> 6);
    int lane = tid & 63;
    const float* xr = x + (size_t)row * 384 + lane;
    float v[6]; float ss = 0.f;
#pragma unroll
    for (int i = 0; i < 6; i++) { v[i] = xr[i * 64]; ss += v[i] * v[i]; }
#pragma unroll
    for (int off = 32; off > 0; off >>= 1) ss += __shfl_xor(ss, off);
    float sc = rsqrtf(ss * (1.f / 384.f) + 1e-6f);
    u16* o = xn + (size_t)row * 384 + lane;
#pragma unroll
    for (int i = 0; i < 6; i++) o[i * 64] = f2bf(v[i] * sc);
  } else if (bid < 11360) {             // ---- tiled transposes ----
    int b = bid - 8192;
    const float* src; u16* dst; int C, DS, R0, C0;
    if (b < 2304) {
      int mlp = b / 1152, r = b % 1152;
      if (r < 768) {
        int L = r / 256, t = r % 256;
        R0 = (t / 16) * 32; C0 = (t % 16) * 32;
        src = (mlp ? r2lw : r1lw) + (size_t)L * 262144;
        dst = lwT + (size_t)(mlp * 3 + L) * 262144;
        C = 512; DS = 512;
      } else {
        int t = r - 768;
        R0 = (t / 24) * 32; C0 = (t % 24) * 32;
        src = mlp ? r2ow : r1ow;
        dst = owT + (size_t)mlp * 393216;
        C = 768; DS = 512;
      }
    } else {
      int t = b - 2304;
      if (t < 288)      { R0 = (t / 24) * 32; C0 = (t % 24) * 32;
                          src = Wu; C = 768; dst = Wuvt;             DS = 384; }
      else if (t < 576) { int t2 = t - 288; R0 = (t2 / 24) * 32; C0 = (t2 % 24) * 32;
                          src = Wv; C = 768; dst = Wuvt + 768 * 384; DS = 384; }
      else              { int t2 = t - 576; R0 = (t2 / 12) * 32; C0 = (t2 % 12) * 32;
                          src = Wo; C = 384; dst = Wot;              DS = 768; }
    }
    int lx = tid % 32, ly = tid / 32;
#pragma unroll
    for (int q = 0; q < 4; q++) {
      int y = q * 8 + ly;
      sm[y][lx] = src[(size_t)(R0 + y) * C + C0 + lx];
    }
    __syncthreads();
#pragma unroll
    for (int q = 0; q < 4; q++) {
      int y = q * 8 + ly;
      dst[(size_t)(C0 + y) * DS + R0 + lx] = f2bf(sm[lx][y]);
    }
  } else {                              // ---- rpe input layer ----
    int idx = (bid - 11360) * 256 + tid;
    int gid = idx * 4;
    int row = gid >> 9, col = gid & 511;
    int mlp = row >> 7, p = row & 127;
    float pos = (p < 64) ? (float)p : ((p == 64) ? 0.f : (float)(p - 128));
    const float* pw = (mlp ? r2pw : r1pw) + col;
    const float* pb = (mlp ? r2pb : r1pb) + col;
    f32x4 w = *(const f32x4*)pw;
    f32x4 bb = *(const f32x4*)pb;
    f32x4 o;
#pragma unroll
    for (int e = 0; e < 4; e++) o[e] = fmaxf(pos * w[e] + bb[e], 0.f);
    *(f32x4*)(X0 + gid) = o;
  }
}

// ---------------------------------------------------------------------------
// RPE layer GEMM (R6).  X (128x512 fp32 per mlp) -> relu(srms(X)) @ WT^T + b.
// grid = 2*(N/64); block owns 128(M) x 64(N) output, full K=512.
// B-slice (64x512 bf16, 64KB) staged ONCE via global_load_lds burst (src
// pre-swizzled); A double-buffered 128x64 tiles, reg-prefetched, swizzled.
// 4 waves: wave w = m-rows [32w,32w+32), acc[2][4].
// TOUT=true: store transposed (C,128) for conv.
// ---------------------------------------------------------------------------
template <int N, bool TOUT>
__global__ __launch_bounds__(256) void rpe_layer_k(
    const float* __restrict__ X,
    const u16* __restrict__ wtA, const u16* __restrict__ wtB,
    const float* __restrict__ bA, const float* __restrict__ bB,
    float* __restrict__ outA, float* __restrict__ outB) {
  constexpr int NSL = N / 64;
  const int mlp = blockIdx.x / NSL;
  const int n0  = (blockIdx.x % NSL) * 64;
  const u16* WT = mlp ? wtB : wtA;
  const float* bias = mlp ? bB : bA;
  float* out = mlp ? outB : outA;
  const float* Xm = X + (size_t)mlp * 128 * 512;

  __shared__ __align__(16) u16 Bs[64 * 512];     // 64 KB, swizzled (8-chunk grp)
  __shared__ __align__(16) u16 As[2][128 * 64];  // 2 x 16 KB, swizzled
  __shared__ float scale[128];

  const int tid  = threadIdx.x;
  const int lane = tid & 63;
  const int w    = tid >> 6;
  const int fl   = lane & 15, fh = lane >> 4;

  // ---- 1: issue ALL B gloads (row = r*4+w, lane = 16B chunk 0..63) ----
#pragma unroll
  for (int r = 0; r < 16; r++) {
    int row  = r * 4 + w;
    int csrc = (lane & ~7) | ((lane & 7) ^ (row & 7));
    gload_lds16(WT + (size_t)(n0 + row) * 512 + csrc * 8,
                Bs + row * 512 + lane * 8);
  }

  // ---- 2: per-row sumsq -> scale (2 threads/row) ----
  {
    int row = tid >> 1, half = tid & 1;
    const float* xr = Xm + (size_t)row * 512 + half * 256;
    float ss = 0.f;
#pragma unroll 8
    for (int q = 0; q < 64; q++) {
      f32x4 v = *(const f32x4*)(xr + q * 4);
      ss += v[0] * v[0] + v[1] * v[1] + v[2] * v[2] + v[3] * v[3];
    }
    ss += __shfl_xor(ss, 1);
    if (!half) scale[row] = rsqrtf(ss * (1.f / 512.f) + 1e-6f);
  }
  __syncthreads();   // scale visible; B gloads drained

  // per-thread A-staging coords: 4 chunks (row, kc) each k-tile
  int arow[4], akc[4];
  float s_[4];
#pragma unroll
  for (int q = 0; q < 4; q++) {
    int cid = q * 256 + tid;
    arow[q] = cid >> 3;
    akc[q]  = cid & 7;
    s_[q]   = scale[arow[q]];
  }

  // ---- 3: stage A tile 0 ----
#pragma unroll
  for (int q = 0; q < 4; q++) {
    const float* xp = Xm + (size_t)arow[q] * 512 + akc[q] * 8;
    f32x4 v0 = *(const f32x4*)xp;
    f32x4 v1 = *(const f32x4*)(xp + 4);
    u16x8 pk;
#pragma unroll
    for (int e = 0; e < 4; e++) pk[e]     = f2bf(fmaxf(v0[e], 0.f) * s_[q]);
#pragma unroll
    for (int e = 0; e < 4; e++) pk[4 + e] = f2bf(fmaxf(v1[e], 0.f) * s_[q]);
    *(u16x8*)(&As[0][arow[q] * 64 + ((akc[q] ^ (arow[q] & 7)) * 8)]) = pk;
  }
  __syncthreads();

  f32x4 acc[2][4];
  {
    f32x4 z = {0.f, 0.f, 0.f, 0.f};
#pragma unroll
    for (int i = 0; i < 2; i++)
#pragma unroll
      for (int j = 0; j < 4; j++) acc[i][j] = z;
  }

  // ---- 4: K loop (8 tiles), dbuf + reg prefetch ----
  for (int kti = 0; kti < 8; kti++) {
    const int cur = kti & 1;
    f32x4 pf0[4], pf1[4];
    if (kti < 7) {
#pragma unroll
      for (int q = 0; q < 4; q++) {
        const float* xp = Xm + (size_t)arow[q] * 512 + (kti + 1) * 64 + akc[q] * 8;
        pf0[q] = *(const f32x4*)xp;
        pf1[q] = *(const f32x4*)(xp + 4);
      }
    }
#pragma unroll
    for (int ks = 0; ks < 2; ks++) {
      const int xc = ((ks * 4 + fh) ^ (fl & 7)) * 8;
      s16x8 af[2], bfr[4];
#pragma unroll
      for (int i = 0; i < 2; i++)
        af[i] = *(const s16x8*)(&As[cur][(w * 32 + i * 16 + fl) * 64 + xc]);
#pragma unroll
      for (int j = 0; j < 4; j++)
        bfr[j] = *(const s16x8*)(&Bs[(j * 16 + fl) * 512 + kti * 64 + xc]);
#pragma unroll
      for (int i = 0; i < 2; i++)
#pragma unroll
        for (int j = 0; j < 4; j++)
          acc[i][j] = __builtin_amdgcn_mfma_f32_16x16x32_bf16(af[i], bfr[j], acc[i][j], 0, 0, 0);
    }
    if (kti < 7) {
#pragma unroll
      for (int q = 0; q < 4; q++) {
        u16x8 pk;
#pragma unroll
        for (int e = 0; e < 4; e++) pk[e]     = f2bf(fmaxf(pf0[q][e], 0.f) * s_[q]);
#pragma unroll
        for (int e = 0; e < 4; e++) pk[4 + e] = f2bf(fmaxf(pf1[q][e], 0.f) * s_[q]);
        *(u16x8*)(&As[cur ^ 1][arow[q] * 64 + ((akc[q] ^ (arow[q] & 7)) * 8)]) = pk;
      }
    }
    __syncthreads();
  }

  // ---- 5: epilogue ----
#pragma unroll
  for (int i = 0; i < 2; i++)
#pragma unroll
    for (int j = 0; j < 4; j++) {
      int c = n0 + j * 16 + fl;
      float bv_ = bias[c];
#pragma unroll
      for (int q = 0; q < 4; q++) {
        int r = w * 32 + i * 16 + fh * 4 + q;
        if (TOUT) out[(size_t)c * 128 + r] = acc[i][j][q] + bv_;
        else      out[(size_t)r * N + c]   = acc[i][j][q] + bv_;
      }
    }
}

// ---------------------------------------------------------------------------
// gemm0_k: [u|v] projection.  C[m][n] = sum_k xn[m][k]*Wuvt[n][k].
// 128x128 tile, BK=64, 4 waves, XOR-swizzled LDS (pre-swizzled global src).
// Epilogue: silu(C+bias) -> uT (n<768) / vT (n>=768), both (C,M) transposed.
// ---------------------------------------------------------------------------
__global__ __launch_bounds__(256) void gemm0_k(
    const u16* __restrict__ A, const u16* __restrict__ Bt,
    u16* __restrict__ u_out, u16* __restrict__ vt_out,
    const float* __restrict__ bu, const float* __restrict__ bv) {
  __shared__ __align__(16) char smem[34816];
  u16*   As  = (u16*)smem;
  u16*   Bs  = As + 128 * 64;
  float* epi = (float*)smem;

  const int tid  = threadIdx.x;
  const int lane = tid & 63;
  const int wid  = tid >> 6;
  const int wm   = wid >> 1, wn = wid & 1;
  const int bm   = blockIdx.x & 255, bn = blockIdx.x >> 8;
  const int m0   = bm * 128, n0 = bn * 128;
  const int fl   = lane & 15, fh = lane >> 4;
  const int K    = 384;

  f32x4 acc[4][4];
  {
    f32x4 z = {0.f, 0.f, 0.f, 0.f};
#pragma unroll
    for (int i = 0; i < 4; i++)
#pragma unroll
      for (int j = 0; j < 4; j++) acc[i][j] = z;
  }

  const int sr  = tid >> 3;
  const int scl = (tid & 7) * 8;
  const int scs = ((tid & 7) ^ (sr & 7)) * 8;

  for (int kt = 0; kt < K; kt += 64) {
    const u16* gA = A  + (size_t)(m0 + sr) * K + kt + scs;
    const u16* gB = Bt + (size_t)(n0 + sr) * K + kt + scs;
    u16* lA = As + sr * 64 + scl;
    u16* lB = Bs + sr * 64 + scl;
#pragma unroll
    for (int i = 0; i < 4; i++) {
      gload_lds16(gA + (size_t)(i * 32) * K, lA + i * 32 * 64);
      gload_lds16(gB + (size_t)(i * 32) * K, lB + i * 32 * 64);
    }
    __syncthreads();
#pragma unroll
    for (int ks = 0; ks < 2; ks++) {
      s16x8 af[4], bfr[4];
      const int xc = ((ks * 4 + fh) ^ (fl & 7)) * 8;
      const u16* ap = As + (wm * 64 + fl) * 64 + xc;
      const u16* bp = Bs + (wn * 64 + fl) * 64 + xc;
#pragma unroll
      for (int i = 0; i < 4; i++) af[i] = *(const s16x8*)(ap + i * 16 * 64);
#pragma unroll
      for (int j = 0; j < 4; j++) bfr[j] = *(const s16x8*)(bp + j * 16 * 64);
#pragma unroll
      for (int i = 0; i < 4; i++)
#pragma unroll
        for (int j = 0; j < 4; j++)
          acc[i][j] = __builtin_amdgcn_mfma_f32_16x16x32_bf16(af[i], bfr[j], acc[i][j], 0, 0, 0);
    }
    __syncthreads();
  }

  for (int half = 0; half < 2; half++) {
    __syncthreads();
    if (wm == half) {
#pragma unroll
      for (int i = 0; i < 4; i++)
#pragma unroll
        for (int j = 0; j < 4; j++) {
          int er = i * 16 + fh * 4;
          int ec = wn * 64 + j * 16 + fl;
#pragma unroll
          for (int q = 0; q < 4; q++) epi[(er + q) * 132 + ec] = acc[i][j][q];
        }
    }
    __syncthreads();
    const bool isU = (n0 < 768);
    u16* baseo = isU ? u_out : vt_out;
    const int cc = tid >> 1;
    const int cg = (isU ? n0 : n0 - 768) + cc;
    const float bias_v = (isU ? bu : bv)[cg];
    u16* dst = baseo + (size_t)cg * M_TOT + m0 + half * 64;
#pragma unroll
    for (int q = 0; q < 4; q++) {
      int mb = (tid & 1) * 8 + q * 16;
      u16x8 pk;
#pragma unroll
      for (int e = 0; e < 8; e++) {
        int mm = mb + e;
        pk[e] = f2bf(silu_f(epi[mm * 132 + cc] + bias_v));
      }
      *(u16x8*)(dst + mb) = pk;
    }
  }
}

// ---------------------------------------------------------------------------
// gemm2_k: out[m][n] = sum_k gT[k][m]*Wot[n][k] + bo[n] + x[m][n].
// Tile 128(M) x 384(N=full), BK=64, 512 threads (8 waves: 2m x 4n).
// A staged from k-major gT via coalesced 256B row-runs + swizzled scatter.
// ---------------------------------------------------------------------------
__global__ __launch_bounds__(512, 2) void gemm2_k(
    const u16* __restrict__ gT, const u16* __restrict__ Wot,
    float* __restrict__ out, const float* __restrict__ bo,
    const float* __restrict__ xres) {
  __shared__ __align__(16) u16 As[128 * 64];   // 16 KB, swizzled
  __shared__ __align__(16) u16 Bs[384 * 64];   // 48 KB, swizzled

  const int tid  = threadIdx.x;
  const int lane = tid & 63;
  const int wid  = tid >> 6;        // 0..7
  const int wm   = wid >> 2;        // 0..1
  const int wn   = wid & 3;         // 0..3
  const int m0   = blockIdx.x * 128;
  const int fl   = lane & 15, fh = lane >> 4;

  f32x4 acc[4][6];
  {
    f32x4 z = {0.f, 0.f, 0.f, 0.f};
#pragma unroll
    for (int i = 0; i < 4; i++)
#pragma unroll
      for (int j = 0; j < 6; j++) acc[i][j] = z;
  }

  const int sr  = tid >> 3;                    // 0..63 (B staging row)
  const int scl = (tid & 7) * 8;
  const int scs = ((tid & 7) ^ (sr & 7)) * 8;

  for (int kt = 0; kt < 768; kt += 64) {
    // B: 6 x gload_lds (384 rows x 64 k)
#pragma unroll
    for (int i = 0; i < 6; i++)
      gload_lds16(Wot + (size_t)(sr + 64 * i) * 768 + kt + scs,
                  Bs + (sr + 64 * i) * 64 + scl);
    // A: 2 rounds, each 16-lane group reads 256B contiguous from one gT row
#pragma unroll
    for (int r = 0; r < 2; r++) {
      int cid = r * 512 + tid;
      int row = cid >> 4;          // k-row 0..63
      int cm  = cid & 15;          // m-chunk (8 elems)
      const u16* ga = gT + (size_t)(kt + row) * M_TOT + m0 + cm * 8;
      u16x8 rv = *(const u16x8*)ga;
      int kc = row >> 3, of = row & 7;
#pragma unroll
      for (int e = 0; e < 8; e++)
        As[(cm * 8 + e) * 64 + ((kc ^ e) << 3) + of] = rv[e];
    }
    __syncthreads();
#pragma unroll
    for (int ks = 0; ks < 2; ks++) {
      s16x8 af[4], bfr[6];
      const int xc = ((ks * 4 + fh) ^ (fl & 7)) * 8;
      const u16* ap = As + (wm * 64 + fl) * 64 + xc;
      const u16* bp = Bs + (wn * 96 + fl) * 64 + xc;
#pragma unroll
      for (int i = 0; i < 4; i++) af[i] = *(const s16x8*)(ap + i * 16 * 64);
#pragma unroll
      for (int j = 0; j < 6; j++) bfr[j] = *(const s16x8*)(bp + j * 16 * 64);
#pragma unroll
      for (int i = 0; i < 4; i++)
#pragma unroll
        for (int j = 0; j < 6; j++)
          acc[i][j] = __builtin_amdgcn_mfma_f32_16x16x32_bf16(af[i], bfr[j], acc[i][j], 0, 0, 0);
    }
    __syncthreads();
  }

  float bov[6];
#pragma unroll
  for (int j = 0; j < 6; j++) bov[j] = bo[wn * 96 + j * 16 + fl];
#pragma unroll
  for (int i = 0; i < 4; i++) {
#pragma unroll
    for (int q = 0; q < 4; q++) {
      int m = m0 + wm * 64 + i * 16 + fh * 4 + q;
      const float* xr = xres + (size_t)m * 384;
      float* orow = out + (size_t)m * 384;
#pragma unroll
      for (int j = 0; j < 6; j++) {
        int n = wn * 96 + j * 16 + fl;
        orow[n] = acc[i][j][q] + bov[j] + xr[n];
      }
    }
  }
}

// ---------------------------------------------------------------------------
// conv_k: MFMA Toeplitz conv + u-gate.  Block = channel c (grid 768),
// loops b=0..7.  Th/Tw built once per block (reversed coeff buffers).
// ---------------------------------------------------------------------------
__global__ __launch_bounds__(256) void conv_k(const u16* __restrict__ vt,
                                              const u16* __restrict__ ut,
                                              const float* __restrict__ a_hT,
                                              const float* __restrict__ a_wT,
                                              u16* __restrict__ gT) {
  __shared__ __align__(16) u16 Th[64 * 72];
  __shared__ __align__(16) u16 Tw[64 * 72];
  __shared__ __align__(16) u16 Vs[64 * 72];
  __shared__ __align__(16) u16 VTs[64 * 72];
  __shared__ __align__(16) u16 Us[64 * 72];
  __shared__ float ahr[192];
  __shared__ float awr[192];
  u16* epi = VTs;

  const int tid = threadIdx.x;
  const int c = blockIdx.x;
  const int lane = tid & 63, w = tid >> 6;
  const int fl = lane & 15, fh = lane >> 4;

  if (tid < 192) {
    int idx = (128 - tid) & 127;
    ahr[tid] = a_hT[(size_t)c * 128 + idx];
    awr[tid] = a_wT[(size_t)c * 128 + idx];
  }
  __syncthreads();

  {
    int y = tid & 63, j0 = (tid >> 6) * 16;
    int base = 128 - y + j0;
    u16x8 p0, p1, q0, q1;
#pragma unroll
    for (int e = 0; e < 8; e++) {
      p0[e] = f2bf(ahr[base + e]);
      p1[e] = f2bf(ahr[base + 8 + e]);
      q0[e] = f2bf(awr[base + e]);
      q1[e] = f2bf(awr[base + 8 + e]);
    }
    *(u16x8*)(Th + y * 72 + j0)     = p0;
    *(u16x8*)(Th + y * 72 + j0 + 8) = p1;
    *(u16x8*)(Tw + y * 72 + j0)     = q0;
    *(u16x8*)(Tw + y * 72 + j0 + 8) = q1;
  }

  const int sy = tid >> 2, sx = (tid & 3) * 16;
  const int ty = tid & 63, tj = (tid >> 6) * 16;

  for (int b = 0; b < 8; b++) {
    const u16* srcv = vt + (size_t)c * M_TOT + b * 4096;
    const u16* srcu = ut + (size_t)c * M_TOT + b * 4096;
    *(u16x8*)(Vs + sy * 72 + sx)     = *(const u16x8*)(srcv + sy * 64 + sx);
    *(u16x8*)(Vs + sy * 72 + sx + 8) = *(const u16x8*)(srcv + sy * 64 + sx + 8);
    *(u16x8*)(Us + sy * 72 + sx)     = *(const u16x8*)(srcu + sy * 64 + sx);
    *(u16x8*)(Us + sy * 72 + sx + 8) = *(const u16x8*)(srcu + sy * 64 + sx + 8);
    __syncthreads();

    {
      u16x8 q0 = *(const u16x8*)(Vs + ty * 72 + tj);
      u16x8 q1 = *(const u16x8*)(Vs + ty * 72 + tj + 8);
#pragma unroll
      for (int e = 0; e < 8; e++) VTs[(tj + e) * 72 + ty]     = q0[e];
#pragma unroll
      for (int e = 0; e < 8; e++) VTs[(tj + 8 + e) * 72 + ty] = q1[e];
    }
    __syncthreads();

    f32x4 acc[4];
    {
      f32x4 z = {0.f, 0.f, 0.f, 0.f};
#pragma unroll
      for (int i = 0; i < 4; i++) acc[i] = z;
    }
#pragma unroll
    for (int ks = 0; ks < 2; ks++) {
      s16x8 qh = *(const s16x8*)(Th + (w * 16 + fl) * 72 + ks * 32 + fh * 8);
#pragma unroll
      for (int i = 0; i < 4; i++) {
        s16x8 p = *(const s16x8*)(VTs + (i * 16 + fl) * 72 + ks * 32 + fh * 8);
        acc[i] = __builtin_amdgcn_mfma_f32_16x16x32_bf16(p, qh, acc[i], 0, 0, 0);
      }
      s16x8 qw = *(const s16x8*)(Vs + (w * 16 + fl) * 72 + ks * 32 + fh * 8);
#pragma unroll
      for (int i = 0; i < 4; i++) {
        s16x8 p = *(const s16x8*)(Tw + (i * 16 + fl) * 72 + ks * 32 + fh * 8);
        acc[i] = __builtin_amdgcn_mfma_f32_16x16x32_bf16(p, qw, acc[i], 0, 0, 0);
      }
    }
    __syncthreads();

    {
      int y = w * 16 + fl;
#pragma unroll
      for (int i = 0; i < 4; i++) {
        u16x4 uq = *(const u16x4*)(Us + y * 72 + i * 16 + fh * 4);
        u16x4 pk;
#pragma unroll
        for (int e = 0; e < 4; e++) pk[e] = f2bf(acc[i][e] * bf2f(uq[e]));
        *(u16x4*)(epi + y * 72 + i * 16 + fh * 4) = pk;
      }
    }
    __syncthreads();

    {
      u16x8 a0 = *(const u16x8*)(epi + sy * 72 + sx);
      u16x8 a1 = *(const u16x8*)(epi + sy * 72 + sx + 8);
      u16* dst = gT + (size_t)c * M_TOT + b * 4096 + sy * 64 + sx;
      *(u16x8*)dst = a0;
      *(u16x8*)(dst + 8) = a1;
    }
    __syncthreads();
  }
}

// ---------------------------------------------------------------------------
extern "C" void kernel_launch(void* const* d_in, const int* in_sizes, int n_in,
                              void* d_out, int out_size, void* d_ws, size_t ws_size,
                              hipStream_t stream) {
  const float* x    = (const float*)d_in[0];
  const float* Wu   = (const float*)d_in[3];
  const float* bu   = (const float*)d_in[4];
  const float* Wv   = (const float*)d_in[5];
  const float* bv   = (const float*)d_in[6];
  const float* Wo   = (const float*)d_in[7];
  const float* bo   = (const float*)d_in[8];
  const float* r1pw = (const float*)d_in[9];
  const float* r1pb = (const float*)d_in[10];
  const float* r1lw = (const float*)d_in[11];
  const float* r1lb = (const float*)d_in[12];
  const float* r1ow = (const float*)d_in[13];
  const float* r1ob = (const float*)d_in[14];
  const float* r2pw = (const float*)d_in[15];
  const float* r2pb = (const float*)d_in[16];
  const float* r2lw = (const float*)d_in[17];
  const float* r2lb = (const float*)d_in[18];
  const float* r2ow = (const float*)d_in[19];
  const float* r2ob = (const float*)d_in[20];
  float* outp = (float*)d_out;

  char* ws = (char*)d_ws;
  size_t off = 0;
  auto carve = [&](size_t bytes) {
    char* p = ws + off;
    off += (bytes + 255) & ~(size_t)255;
    return p;
  };
  u16*   xn   = (u16*)carve((size_t)M_TOT * 384 * 2);
  u16*   uT   = (u16*)carve((size_t)768 * M_TOT * 2);
  u16*   vT   = (u16*)carve((size_t)768 * M_TOT * 2);
  u16*   gT   = (u16*)carve((size_t)768 * M_TOT * 2);
  u16*   Wuvt = (u16*)carve((size_t)1536 * 384 * 2);
  u16*   Wot  = (u16*)carve((size_t)384 * 768 * 2);
  float* awT  = (float*)carve((size_t)768 * 128 * 4);
  float* ahT  = (float*)carve((size_t)768 * 128 * 4);

  // RPE scratch aliased into gT region (gT written only later, by conv_k)
  char* rb  = (char*)gT;
  u16*   lwT = (u16*)rb;                               // 3 MB
  u16*   owT = (u16*)(rb + 3145728);                   // 1.5 MB
  float* X0  = (float*)(rb + 3145728 + 1572864);
  float* X1  = X0 + 256 * 512;

  setup_k<<<11488, 256, 0, stream>>>(x, xn, Wu, Wv, Wo, Wuvt, Wot,
                                     r1lw, r1ow, r2lw, r2ow, lwT, owT,
                                     r1pw, r1pb, r2pw, r2pb, X0);

  rpe_layer_k<512, false><<<16, 256, 0, stream>>>(X0, lwT, lwT + 3 * 262144,
                                                  r1lb, r2lb, X1, X1 + 128 * 512);
  rpe_layer_k<512, false><<<16, 256, 0, stream>>>(X1, lwT + 262144, lwT + 4 * 262144,
                                                  r1lb + 512, r2lb + 512, X0, X0 + 128 * 512);
  rpe_layer_k<512, false><<<16, 256, 0, stream>>>(X0, lwT + 2 * 262144, lwT + 5 * 262144,
                                                  r1lb + 1024, r2lb + 1024, X1, X1 + 128 * 512);
  rpe_layer_k<768, true><<<24, 256, 0, stream>>>(X1, owT, owT + 393216,
                                                 r1ob, r2ob, awT, ahT);

  // u|v GEMM: M=32768, N=1536, K=384 -> uT, vT (both (C,M))
  gemm0_k<<<256 * 12, 256, 0, stream>>>(xn, Wuvt, uT, vT, bu, bv);
  // conv + gate -> gT (C,M); block = channel
  conv_k<<<768, 256, 0, stream>>>(vT, uT, ahT, awT, gT);
  // out GEMM: M=32768, N=384(full), K=768 (+bo +x residual)
  gemm2_k<<<256, 512, 0, stream>>>(gT, Wot, outp, bo, x);
}